// Round 1
// baseline (4109.318 us; speedup 1.0000x reference)
//
#include <hip/hip_runtime.h>
#include <math.h>

// Problem dims (fixed by reference)
#define DIM    768
#define NB     16
#define SEQ    1024
#define NTOK   (NB*SEQ)        // 16384
#define HEADS  12
#define HD     64
#define HMLP   3072
#define QKVN   2304

// ---------------------------------------------------------------------------
// LayerNorm: one block per token, 256 threads, 3 elems/thread.
// ---------------------------------------------------------------------------
__global__ __launch_bounds__(256) void ln_kernel(const float* __restrict__ x,
                                                 const float* __restrict__ g,
                                                 const float* __restrict__ b,
                                                 float* __restrict__ out) {
    const int t = blockIdx.x;
    const float* xp = x + (size_t)t * DIM;
    float v[3];
    float s = 0.f, ss = 0.f;
#pragma unroll
    for (int u = 0; u < 3; ++u) {
        v[u] = xp[threadIdx.x + 256 * u];
        s += v[u];
        ss += v[u] * v[u];
    }
#pragma unroll
    for (int m = 1; m < 64; m <<= 1) {
        s  += __shfl_xor(s, m);
        ss += __shfl_xor(ss, m);
    }
    __shared__ float rs[4], rss[4];
    const int wave = threadIdx.x >> 6;
    if ((threadIdx.x & 63) == 0) { rs[wave] = s; rss[wave] = ss; }
    __syncthreads();
    s  = rs[0] + rs[1] + rs[2] + rs[3];
    ss = rss[0] + rss[1] + rss[2] + rss[3];
    const float mu  = s * (1.0f / DIM);
    const float var = ss * (1.0f / DIM) - mu * mu;
    const float rst = 1.0f / sqrtf(var + 1e-5f);
    float* op = out + (size_t)t * DIM;
#pragma unroll
    for (int u = 0; u < 3; ++u) {
        const int c = threadIdx.x + 256 * u;
        op[c] = (v[u] - mu) * rst * g[c] + b[c];
    }
}

// ---------------------------------------------------------------------------
// Tiled fp32 GEMM: C[M,N] = A[M,K] @ B[N,K]^T (+bias, +epilogue)
// BM=BN=64, BK=32, 256 threads, 4x4 micro-tile per thread.
// LDS tiles stored transposed (As[k][m], Bs[k][n]) so the inner loop is
// 2x ds_read_b128 : 16 v_fma_f32 per k-step.
// EPI: 0 = +bias ; 1 = +bias +residual ; 2 = gelu(+bias) exact (erf)
// ---------------------------------------------------------------------------
template <int EPI>
__global__ __launch_bounds__(256) void gemm_kernel(const float* __restrict__ A,
                                                   const float* __restrict__ Bw,
                                                   const float* __restrict__ bias,
                                                   const float* __restrict__ res,
                                                   float* __restrict__ C,
                                                   int M, int N, int K) {
    const int BK = 32;
    const int LD = 68;                 // 68 floats = 272 B, multiple of 16 B
    __shared__ float As[BK * LD];
    __shared__ float Bs[BK * LD];

    const int n0 = blockIdx.x * 64;
    const int m0 = blockIdx.y * 64;
    const int tid = threadIdx.x;
    const int tm = tid >> 4;           // 0..15
    const int tn = tid & 15;           // 0..15
    const int lr = tid >> 3;           // 0..31 (load row)
    const int lk = (tid & 7) * 4;      // 0,4,...,28 (load k)

    float acc[4][4] = {};

    for (int k0 = 0; k0 < K; k0 += BK) {
#pragma unroll
        for (int h = 0; h < 2; ++h) {
            const int r = lr + h * 32;
            const float4 va = *(const float4*)(A  + (size_t)(m0 + r) * K + k0 + lk);
            const float4 vb = *(const float4*)(Bw + (size_t)(n0 + r) * K + k0 + lk);
            As[(lk + 0) * LD + r] = va.x; As[(lk + 1) * LD + r] = va.y;
            As[(lk + 2) * LD + r] = va.z; As[(lk + 3) * LD + r] = va.w;
            Bs[(lk + 0) * LD + r] = vb.x; Bs[(lk + 1) * LD + r] = vb.y;
            Bs[(lk + 2) * LD + r] = vb.z; Bs[(lk + 3) * LD + r] = vb.w;
        }
        __syncthreads();
#pragma unroll
        for (int kk = 0; kk < BK; ++kk) {
            const float4 a4 = *(const float4*)&As[kk * LD + tm * 4];
            const float4 b4 = *(const float4*)&Bs[kk * LD + tn * 4];
            const float av[4] = {a4.x, a4.y, a4.z, a4.w};
            const float bv[4] = {b4.x, b4.y, b4.z, b4.w};
#pragma unroll
            for (int i = 0; i < 4; ++i)
#pragma unroll
                for (int j = 0; j < 4; ++j)
                    acc[i][j] = fmaf(av[i], bv[j], acc[i][j]);
        }
        __syncthreads();
    }

    const float4 bb = *(const float4*)(bias + n0 + tn * 4);
    const float bv[4] = {bb.x, bb.y, bb.z, bb.w};
#pragma unroll
    for (int i = 0; i < 4; ++i) {
        const size_t row = (size_t)(m0 + tm * 4 + i);
        float o[4];
#pragma unroll
        for (int j = 0; j < 4; ++j) {
            float c = acc[i][j] + bv[j];
            if (EPI == 2) c = 0.5f * c * (1.0f + erff(c * 0.70710678118f));
            o[j] = c;
        }
        if (EPI == 1) {
            const float4 rv = *(const float4*)(res + row * N + n0 + tn * 4);
            o[0] += rv.x; o[1] += rv.y; o[2] += rv.z; o[3] += rv.w;
        }
        *(float4*)(C + row * N + n0 + tn * 4) = make_float4(o[0], o[1], o[2], o[3]);
    }
}

// ---------------------------------------------------------------------------
// Flash-style fp32 attention. One block per (q-tile of 64, head, batch).
// qkv layout: [tok][2304] with q at h*64, k at 768+h*64, v at 1536+h*64.
// Online softmax; Q pre-scaled by 1/sqrt(768) (reference scales by sqrt(D)).
// ---------------------------------------------------------------------------
__global__ __launch_bounds__(256) void attn_kernel(const float* __restrict__ qkv,
                                                   float* __restrict__ out) {
    const int LD = 68;
    __shared__ float Qt[64 * LD];  // [d][row]
    __shared__ float Kt[64 * LD];  // [d][key]
    __shared__ float Vs[64 * LD];  // [key][d]
    __shared__ float Pt[64 * LD];  // [key][row]

    const int q0 = blockIdx.x * 64;
    const int h  = blockIdx.y;
    const int b  = blockIdx.z;
    const float SCALE = 0.0360843918f;  // 1/sqrt(768)

    const int tid = threadIdx.x;
    const int r   = tid >> 4;          // 0..15
    const int c4  = (tid & 15) * 4;    // 0..60
    const int tm  = r, tn = tid & 15;

    const size_t base = (size_t)b * SEQ * QKVN + (size_t)h * HD;

#pragma unroll
    for (int it = 0; it < 4; ++it) {
        const int ri = r + it * 16;
        const float4 q = *(const float4*)(qkv + base + (size_t)(q0 + ri) * QKVN + c4);
        Qt[(c4 + 0) * LD + ri] = q.x * SCALE;
        Qt[(c4 + 1) * LD + ri] = q.y * SCALE;
        Qt[(c4 + 2) * LD + ri] = q.z * SCALE;
        Qt[(c4 + 3) * LD + ri] = q.w * SCALE;
    }

    float o[4][4] = {};
    float mrow[4] = {-1e30f, -1e30f, -1e30f, -1e30f};
    float lrow[4] = {};

    for (int kt = 0; kt < 16; ++kt) {
        const int k0 = kt * 64;
        __syncthreads();   // previous iter's Pt/Vs reads done; Q load done (iter 0)
#pragma unroll
        for (int it = 0; it < 4; ++it) {
            const int ri = r + it * 16;
            const float4 kv = *(const float4*)(qkv + base + 768 + (size_t)(k0 + ri) * QKVN + c4);
            Kt[(c4 + 0) * LD + ri] = kv.x;
            Kt[(c4 + 1) * LD + ri] = kv.y;
            Kt[(c4 + 2) * LD + ri] = kv.z;
            Kt[(c4 + 3) * LD + ri] = kv.w;
            const float4 vv = *(const float4*)(qkv + base + 1536 + (size_t)(k0 + ri) * QKVN + c4);
            *(float4*)&Vs[ri * LD + c4] = vv;
        }
        __syncthreads();

        float s[4][4] = {};
#pragma unroll 8
        for (int d = 0; d < 64; ++d) {
            const float4 a4 = *(const float4*)&Qt[d * LD + tm * 4];
            const float4 b4 = *(const float4*)&Kt[d * LD + tn * 4];
            const float av[4] = {a4.x, a4.y, a4.z, a4.w};
            const float bvv[4] = {b4.x, b4.y, b4.z, b4.w};
#pragma unroll
            for (int i = 0; i < 4; ++i)
#pragma unroll
                for (int j = 0; j < 4; ++j)
                    s[i][j] = fmaf(av[i], bvv[j], s[i][j]);
        }

        // online softmax update (rows owned by 16 threads sharing tm)
#pragma unroll
        for (int i = 0; i < 4; ++i) {
            float mx = fmaxf(fmaxf(s[i][0], s[i][1]), fmaxf(s[i][2], s[i][3]));
#pragma unroll
            for (int m = 1; m < 16; m <<= 1) mx = fmaxf(mx, __shfl_xor(mx, m));
            const float mnew  = fmaxf(mrow[i], mx);
            const float alpha = expf(mrow[i] - mnew);
            float rsum = 0.f;
            float p[4];
#pragma unroll
            for (int j = 0; j < 4; ++j) {
                p[j] = expf(s[i][j] - mnew);
                rsum += p[j];
            }
#pragma unroll
            for (int m = 1; m < 16; m <<= 1) rsum += __shfl_xor(rsum, m);
            lrow[i] = lrow[i] * alpha + rsum;
            mrow[i] = mnew;
#pragma unroll
            for (int j = 0; j < 4; ++j) {
                o[i][j] *= alpha;
                Pt[(tn * 4 + j) * LD + tm * 4 + i] = p[j];
            }
        }
        __syncthreads();

        // O += P @ V
#pragma unroll 8
        for (int k = 0; k < 64; ++k) {
            const float4 p4 = *(const float4*)&Pt[k * LD + tm * 4];
            const float4 v4 = *(const float4*)&Vs[k * LD + tn * 4];
            const float pv[4] = {p4.x, p4.y, p4.z, p4.w};
            const float vv[4] = {v4.x, v4.y, v4.z, v4.w};
#pragma unroll
            for (int i = 0; i < 4; ++i)
#pragma unroll
                for (int j = 0; j < 4; ++j)
                    o[i][j] = fmaf(pv[i], vv[j], o[i][j]);
        }
    }

    // write O / l  -> out[b, q, h*64 + c]
#pragma unroll
    for (int i = 0; i < 4; ++i) {
        const int row = q0 + tm * 4 + i;
        const float inv = 1.0f / lrow[i];
        float4 ov = make_float4(o[i][0] * inv, o[i][1] * inv, o[i][2] * inv, o[i][3] * inv);
        *(float4*)(out + ((size_t)(b * SEQ + row)) * DIM + h * HD + tn * 4) = ov;
    }
}

// ---------------------------------------------------------------------------
// Launch
// ---------------------------------------------------------------------------
extern "C" void kernel_launch(void* const* d_in, const int* in_sizes, int n_in,
                              void* d_out, int out_size, void* d_ws, size_t ws_size,
                              hipStream_t stream) {
    const float* x     = (const float*)d_in[0];
    const float* ln_g  = (const float*)d_in[1];
    const float* ln_b  = (const float*)d_in[2];
    const float* w_qkv = (const float*)d_in[3];
    const float* b_qkv = (const float*)d_in[4];
    const float* w_out = (const float*)d_in[5];
    const float* b_out = (const float*)d_in[6];
    const float* w_fc1 = (const float*)d_in[7];
    const float* b_fc1 = (const float*)d_in[8];
    const float* w_fc2 = (const float*)d_in[9];
    const float* b_fc2 = (const float*)d_in[10];
    float* out = (float*)d_out;

    // Workspace layout (240 MB total):
    //   ln_buf : 50,331,648 B
    //   qkv    : 150,994,944 B
    //   attn   : 50,331,648 B
    //   hbuf   : overlaps qkv+attn (201,326,592 B) — both dead by FC1.
    char* ws = (char*)d_ws;
    float* ln_buf = (float*)ws;
    float* qkv    = (float*)(ws + 50331648);
    float* attn   = (float*)(ws + 50331648 + 150994944);
    float* hbuf   = qkv;

    // 1. ln1 = layernorm(x)
    ln_kernel<<<NTOK, 256, 0, stream>>>(x, ln_g, ln_b, ln_buf);
    // 2. qkv = ln1 @ w_qkv^T + b_qkv
    gemm_kernel<0><<<dim3(QKVN / 64, NTOK / 64), 256, 0, stream>>>(
        ln_buf, w_qkv, b_qkv, nullptr, qkv, NTOK, QKVN, DIM);
    // 3. attention (flash-style) -> attn
    attn_kernel<<<dim3(SEQ / 64, HEADS, NB), 256, 0, stream>>>(qkv, attn);
    // 4. x1 = x + attn @ w_out^T + b_out   (x1 lives in d_out)
    gemm_kernel<1><<<dim3(DIM / 64, NTOK / 64), 256, 0, stream>>>(
        attn, w_out, b_out, x, out, NTOK, DIM, DIM);
    // 5. ln2 = layernorm(x1)
    ln_kernel<<<NTOK, 256, 0, stream>>>(out, ln_g, ln_b, ln_buf);
    // 6. h = gelu(ln2 @ w_fc1^T + b_fc1)
    gemm_kernel<2><<<dim3(HMLP / 64, NTOK / 64), 256, 0, stream>>>(
        ln_buf, w_fc1, b_fc1, nullptr, hbuf, NTOK, HMLP, DIM);
    // 7. out = x1 + h @ w_fc2^T + b_fc2
    gemm_kernel<1><<<dim3(DIM / 64, NTOK / 64), 256, 0, stream>>>(
        hbuf, w_fc2, b_fc2, out, out, NTOK, DIM, HMLP);
}

// Round 6
// 739.528 us; speedup vs baseline: 5.5567x; 5.5567x over previous
//
#include <hip/hip_runtime.h>
#include <math.h>

// Problem dims (fixed by reference)
#define DIM    768
#define NB     16
#define SEQ    1024
#define NTOK   (NB*SEQ)        // 16384
#define HEADS  12
#define HD     64
#define HMLP   3072
#define QKVN   2304

typedef _Float16 f16x8 __attribute__((ext_vector_type(8)));
typedef _Float16 f16x4 __attribute__((ext_vector_type(4)));
typedef float    f32x4 __attribute__((ext_vector_type(4)));

typedef __attribute__((address_space(3))) unsigned int       lds_u32;
typedef __attribute__((address_space(1))) const unsigned int glb_u32;

// async global->LDS, 16 bytes per lane. LDS dest must be linear in lane order.
__device__ __forceinline__ void gload16(const _Float16* g, _Float16* l) {
    __builtin_amdgcn_global_load_lds((glb_u32*)g, (lds_u32*)l, 16, 0, 0);
}

// ---------------------------------------------------------------------------
// LayerNorm: one block per token, 256 threads, 3 elems/thread. fp32 in, fp16 out.
// ---------------------------------------------------------------------------
__global__ __launch_bounds__(256) void ln_kernel(const float* __restrict__ x,
                                                 const float* __restrict__ g,
                                                 const float* __restrict__ b,
                                                 _Float16* __restrict__ out) {
    const int t = blockIdx.x;
    const float* xp = x + (size_t)t * DIM;
    float v[3];
    float s = 0.f, ss = 0.f;
#pragma unroll
    for (int u = 0; u < 3; ++u) {
        v[u] = xp[threadIdx.x + 256 * u];
        s += v[u];
        ss += v[u] * v[u];
    }
#pragma unroll
    for (int m = 1; m < 64; m <<= 1) {
        s  += __shfl_xor(s, m);
        ss += __shfl_xor(ss, m);
    }
    __shared__ float rs[4], rss[4];
    const int wave = threadIdx.x >> 6;
    if ((threadIdx.x & 63) == 0) { rs[wave] = s; rss[wave] = ss; }
    __syncthreads();
    s  = rs[0] + rs[1] + rs[2] + rs[3];
    ss = rss[0] + rss[1] + rss[2] + rss[3];
    const float mu  = s * (1.0f / DIM);
    const float var = ss * (1.0f / DIM) - mu * mu;
    const float rst = 1.0f / sqrtf(var + 1e-5f);
    _Float16* op = out + (size_t)t * DIM;
#pragma unroll
    for (int u = 0; u < 3; ++u) {
        const int c = threadIdx.x + 256 * u;
        op[c] = (_Float16)((v[u] - mu) * rst * g[c] + b[c]);
    }
}

// ---------------------------------------------------------------------------
// fp32 -> fp16 cast (weights), 4 elems/thread
// ---------------------------------------------------------------------------
__global__ __launch_bounds__(256) void cast_kernel(const float* __restrict__ in,
                                                   _Float16* __restrict__ out, int n) {
    const int i = (blockIdx.x * 256 + threadIdx.x) * 4;
    if (i < n) {
        const float4 v = *(const float4*)(in + i);
        f16x4 o;
        o[0] = (_Float16)v.x; o[1] = (_Float16)v.y;
        o[2] = (_Float16)v.z; o[3] = (_Float16)v.w;
        *(f16x4*)(out + i) = o;
    }
}

// ---------------------------------------------------------------------------
// MFMA fp16 GEMM: C[M,N] = A[M,K] @ B[N,K]^T (+bias, +epilogue), fp32 accum.
// BM=BN=128, BK=32, 256 threads = 4 waves (2x2), 64x64 per wave.
// K-slot swizzle applied on the GLOBAL source; LDS dest linear (rule 21).
// EPI: 0 = +bias ; 1 = +bias +residual(fp32) ; 2 = gelu(+bias) exact
// ---------------------------------------------------------------------------
template <int EPI, typename OUT_T>
__global__ __launch_bounds__(256) void gemm_f16(const _Float16* __restrict__ A,
                                                const _Float16* __restrict__ Bw,
                                                const float* __restrict__ bias,
                                                const float* __restrict__ res,
                                                OUT_T* __restrict__ C,
                                                int M, int N, int K) {
    __shared__ _Float16 As[2][128 * 32];
    __shared__ _Float16 Bs[2][128 * 32];

    const int tid  = threadIdx.x;
    const int lane = tid & 63;
    const int wave = tid >> 6;
    const int wr = wave >> 1;
    const int wc = wave & 1;
    const int n0 = blockIdx.x * 128;
    const int m0 = blockIdx.y * 128;

    const int sr = tid >> 2;           // staging row 0..63
    const int sp = tid & 3;            // staging 16B slot 0..3

    f32x4 acc[4][4] = {};

    auto stage = [&](int buf, int k0) {
#pragma unroll
        for (int h = 0; h < 2; ++h) {
            const int r  = sr + h * 64;
            const int kc = sp ^ ((r >> 1) & 3);
            const size_t goff = (size_t)r * K + k0 + kc * 8;
            gload16(A  + (size_t)m0 * K + goff, &As[buf][tid * 8 + h * 2048]);
            gload16(Bw + (size_t)n0 * K + goff, &Bs[buf][tid * 8 + h * 2048]);
        }
    };

    auto compute = [&](int buf) {
        f16x8 a[4], b[4];
#pragma unroll
        for (int m = 0; m < 4; ++m) {
            const int row = wr * 64 + m * 16 + (lane & 15);
            const int p   = (lane >> 4) ^ ((row >> 1) & 3);
            a[m] = *(const f16x8*)&As[buf][row * 32 + p * 8];
        }
#pragma unroll
        for (int n = 0; n < 4; ++n) {
            const int row = wc * 64 + n * 16 + (lane & 15);
            const int p   = (lane >> 4) ^ ((row >> 1) & 3);
            b[n] = *(const f16x8*)&Bs[buf][row * 32 + p * 8];
        }
#pragma unroll
        for (int m = 0; m < 4; ++m)
#pragma unroll
            for (int n = 0; n < 4; ++n)
                acc[m][n] = __builtin_amdgcn_mfma_f32_16x16x32_f16(a[m], b[n], acc[m][n], 0, 0, 0);
    };

    const int NT = K / 32;
    stage(0, 0);
    __syncthreads();
    int cur = 0;
    for (int t = 0; t < NT; ++t) {
        if (t + 1 < NT) stage(cur ^ 1, (t + 1) * 32);
        compute(cur);
        __syncthreads();
        cur ^= 1;
    }

    const int col0 = n0 + wc * 64 + (lane & 15);
#pragma unroll
    for (int m = 0; m < 4; ++m) {
#pragma unroll
        for (int j = 0; j < 4; ++j) {
            const size_t row = (size_t)(m0 + wr * 64 + m * 16 + (lane >> 4) * 4 + j);
#pragma unroll
            for (int n = 0; n < 4; ++n) {
                const int col = col0 + n * 16;
                float c = acc[m][n][j] + bias[col];
                if (EPI == 2) c = 0.5f * c * (1.0f + erff(c * 0.70710678118f));
                if (EPI == 1) c += res[row * N + col];
                C[row * N + col] = (OUT_T)c;
            }
        }
    }
}

// ---------------------------------------------------------------------------
// MFMA flash attention. Block = 256 thr (4 waves) per (64 q-rows, head, batch).
// Wave w owns q-rows w*16..w*16+15: Q frags in registers.
// K in LDS [key][72] linear; V in LDS transposed Vt[d][key] with 16B-chunk
// XOR swizzle phys_chunk = (key>>3)^(d>>3)  (write ~2-way, read conflict-free).
// Softmax wave-parallel in-register (exp2 domain); P via per-wave LDS strip.
// ---------------------------------------------------------------------------
__global__ __launch_bounds__(256) void attn_kernel(const _Float16* __restrict__ qkv,
                                                   _Float16* __restrict__ out) {
    __shared__ _Float16 K_lds[64 * 72];
    __shared__ _Float16 Vt[64 * 72];
    __shared__ _Float16 P_lds[4][16 * 72];

    const int q0 = blockIdx.x * 64;
    const int h  = blockIdx.y;
    const int b  = blockIdx.z;
    // 1/sqrt(768) * log2(e)
    const float SCALE2 = 0.05205879570f;

    const int tid  = threadIdx.x;
    const int lane = tid & 63;
    const int w    = tid >> 6;
    const int g    = lane >> 4;        // k-group 0..3
    const int c    = lane & 15;        // col within 16

    const int skey = tid >> 3;         // staging key 0..31
    const int sdc  = tid & 7;          // staging d-chunk 0..7

    const size_t base = (size_t)b * SEQ * QKVN + (size_t)h * HD;

    // Q fragments (A-layout): lane holds Q[w*16 + c][kk*32 + g*8 .. +8]
    f16x8 aq[2];
#pragma unroll
    for (int kk = 0; kk < 2; ++kk)
        aq[kk] = *(const f16x8*)(qkv + base + (size_t)(q0 + w * 16 + c) * QKVN + kk * 32 + g * 8);

    f32x4 o[4] = {};                   // O accum: row g*4+j, col d = n*16+c
    float mrow[4] = {-1e30f, -1e30f, -1e30f, -1e30f};
    float lrow[4] = {};

    for (int kt = 0; kt < 16; ++kt) {
        const int k0 = kt * 64;
        __syncthreads();               // prev tile K/Vt reads done
#pragma unroll
        for (int it = 0; it < 2; ++it) {
            const int key = skey + it * 32;
            const f16x8 kv = *(const f16x8*)(qkv + base + 768  + (size_t)(k0 + key) * QKVN + sdc * 8);
            const f16x8 vv = *(const f16x8*)(qkv + base + 1536 + (size_t)(k0 + key) * QKVN + sdc * 8);
            *(f16x8*)&K_lds[key * 72 + sdc * 8] = kv;
            const int pc = (key >> 3) ^ sdc;     // d>>3 == sdc for these 8 elems
#pragma unroll
            for (int e = 0; e < 8; ++e)
                Vt[(sdc * 8 + e) * 72 + pc * 8 + (key & 7)] = vv[e];
        }
        __syncthreads();               // staging visible

        // S = Q @ K^T  (16 q-rows x 64 keys per wave)
        f32x4 s[4] = {};
#pragma unroll
        for (int n = 0; n < 4; ++n) {
#pragma unroll
            for (int kk = 0; kk < 2; ++kk) {
                const f16x8 bk = *(const f16x8*)&K_lds[(n * 16 + c) * 72 + (kk * 4 + g) * 8];
                s[n] = __builtin_amdgcn_mfma_f32_16x16x32_f16(aq[kk], bk, s[n], 0, 0, 0);
            }
        }

        // online softmax (exp2 domain), rows g*4+j reduced over 16-lane groups
        float p[4][4];
#pragma unroll
        for (int j = 0; j < 4; ++j) {
            float sv[4];
#pragma unroll
            for (int n = 0; n < 4; ++n) sv[n] = s[n][j] * SCALE2;
            float mx = fmaxf(fmaxf(sv[0], sv[1]), fmaxf(sv[2], sv[3]));
#pragma unroll
            for (int m = 1; m < 16; m <<= 1) mx = fmaxf(mx, __shfl_xor(mx, m));
            const float mnew  = fmaxf(mrow[j], mx);
            const float alpha = exp2f(mrow[j] - mnew);
            float rsum = 0.f;
#pragma unroll
            for (int n = 0; n < 4; ++n) {
                p[n][j] = exp2f(sv[n] - mnew);
                rsum += p[n][j];
            }
#pragma unroll
            for (int m = 1; m < 16; m <<= 1) rsum += __shfl_xor(rsum, m);
            lrow[j] = lrow[j] * alpha + rsum;
            mrow[j] = mnew;
#pragma unroll
            for (int n = 0; n < 4; ++n) o[n][j] *= alpha;
        }

        // P -> per-wave LDS strip (C-layout scatter, fp16)
#pragma unroll
        for (int j = 0; j < 4; ++j)
#pragma unroll
            for (int n = 0; n < 4; ++n)
                P_lds[w][(g * 4 + j) * 72 + n * 16 + c] = (_Float16)p[n][j];

        // O += P @ V   (A-frag from P_lds, B-frag from swizzled Vt)
#pragma unroll
        for (int kk = 0; kk < 2; ++kk) {
            const f16x8 ap = *(const f16x8*)&P_lds[w][c * 72 + kk * 32 + g * 8];
#pragma unroll
            for (int n = 0; n < 4; ++n) {
                const int dp = n * 16 + c;
                const int pc = (kk * 4 + g) ^ (dp >> 3);
                const f16x8 bv = *(const f16x8*)&Vt[dp * 72 + pc * 8];
                o[n] = __builtin_amdgcn_mfma_f32_16x16x32_f16(ap, bv, o[n], 0, 0, 0);
            }
        }
    }

    // write O/l -> out[b, q0 + w*16 + g*4 + j][h*64 + n*16 + c]
#pragma unroll
    for (int j = 0; j < 4; ++j) {
        const size_t row = (size_t)(b * SEQ + q0 + w * 16 + g * 4 + j);
        const float inv = 1.0f / lrow[j];
#pragma unroll
        for (int n = 0; n < 4; ++n)
            out[row * DIM + h * HD + n * 16 + c] = (_Float16)(o[n][j] * inv);
    }
}

// ---------------------------------------------------------------------------
// Launch
// ---------------------------------------------------------------------------
extern "C" void kernel_launch(void* const* d_in, const int* in_sizes, int n_in,
                              void* d_out, int out_size, void* d_ws, size_t ws_size,
                              hipStream_t stream) {
    const float* x     = (const float*)d_in[0];
    const float* ln_g  = (const float*)d_in[1];
    const float* ln_b  = (const float*)d_in[2];
    const float* w_qkv = (const float*)d_in[3];
    const float* b_qkv = (const float*)d_in[4];
    const float* w_out = (const float*)d_in[5];
    const float* b_out = (const float*)d_in[6];
    const float* w_fc1 = (const float*)d_in[7];
    const float* b_fc1 = (const float*)d_in[8];
    const float* w_fc2 = (const float*)d_in[9];
    const float* b_fc2 = (const float*)d_in[10];
    float* out = (float*)d_out;

    // Workspace layout (bytes):
    //   wq16   @ 0          : 3,538,944
    //   wo16   @ 3,538,944  : 1,179,648
    //   wf1_16 @ 4,718,592  : 4,718,592
    //   wf2_16 @ 9,437,184  : 4,718,592
    //   ln16   @ 14,155,776 : 25,165,824
    //   qkv16  @ 39,321,600 : 75,497,472
    //   attn16 @114,819,072 : 25,165,824
    //   h16    @ 39,321,600 : 100,663,296 (overlaps qkv16+attn16; both dead by FC1)
    char* ws = (char*)d_ws;
    _Float16* wq16   = (_Float16*)(ws);
    _Float16* wo16   = (_Float16*)(ws + 3538944);
    _Float16* wf1_16 = (_Float16*)(ws + 4718592);
    _Float16* wf2_16 = (_Float16*)(ws + 9437184);
    _Float16* ln16   = (_Float16*)(ws + 14155776);
    _Float16* qkv16  = (_Float16*)(ws + 39321600);
    _Float16* attn16 = (_Float16*)(ws + 114819072);
    _Float16* h16    = qkv16;

    // weight casts (fp32 -> fp16)
    cast_kernel<<<(QKVN * DIM) / 1024, 256, 0, stream>>>(w_qkv, wq16, QKVN * DIM);
    cast_kernel<<<(DIM * DIM) / 1024, 256, 0, stream>>>(w_out, wo16, DIM * DIM);
    cast_kernel<<<(HMLP * DIM) / 1024, 256, 0, stream>>>(w_fc1, wf1_16, HMLP * DIM);
    cast_kernel<<<(DIM * HMLP) / 1024, 256, 0, stream>>>(w_fc2, wf2_16, DIM * HMLP);

    // 1. ln1 = layernorm(x) -> fp16
    ln_kernel<<<NTOK, 256, 0, stream>>>(x, ln_g, ln_b, ln16);
    // 2. qkv = ln1 @ w_qkv^T + b_qkv -> fp16
    gemm_f16<0, _Float16><<<dim3(QKVN / 128, NTOK / 128), 256, 0, stream>>>(
        ln16, wq16, b_qkv, nullptr, qkv16, NTOK, QKVN, DIM);
    // 3. attention (MFMA flash) -> fp16
    attn_kernel<<<dim3(SEQ / 64, HEADS, NB), 256, 0, stream>>>(qkv16, attn16);
    // 4. x1 = x + attn @ w_out^T + b_out -> d_out (fp32)
    gemm_f16<1, float><<<dim3(DIM / 128, NTOK / 128), 256, 0, stream>>>(
        attn16, wo16, b_out, x, out, NTOK, DIM, DIM);
    // 5. ln2 = layernorm(x1) -> fp16
    ln_kernel<<<NTOK, 256, 0, stream>>>(out, ln_g, ln_b, ln16);
    // 6. h = gelu(ln2 @ w_fc1^T + b_fc1) -> fp16
    gemm_f16<2, _Float16><<<dim3(HMLP / 128, NTOK / 128), 256, 0, stream>>>(
        ln16, wf1_16, b_fc1, nullptr, h16, NTOK, HMLP, DIM);
    // 7. out = x1 + h @ w_fc2^T + b_fc2 -> d_out (fp32)
    gemm_f16<1, float><<<dim3(DIM / 128, NTOK / 128), 256, 0, stream>>>(
        h16, wf2_16, b_fc2, out, out, NTOK, DIM, HMLP);
}

// Round 7
// 705.449 us; speedup vs baseline: 5.8251x; 1.0483x over previous
//
#include <hip/hip_runtime.h>
#include <math.h>

// Problem dims (fixed by reference)
#define DIM    768
#define NB     16
#define SEQ    1024
#define NTOK   (NB*SEQ)        // 16384
#define HEADS  12
#define HD     64
#define HMLP   3072
#define QKVN   2304

typedef _Float16 f16x8 __attribute__((ext_vector_type(8)));
typedef _Float16 f16x4 __attribute__((ext_vector_type(4)));
typedef float    f32x4 __attribute__((ext_vector_type(4)));

typedef __attribute__((address_space(3))) unsigned int       lds_u32;
typedef __attribute__((address_space(1))) const unsigned int glb_u32;

// async global->LDS, 16 bytes per lane. LDS dest must be linear in lane order.
__device__ __forceinline__ void gload16(const _Float16* g, _Float16* l) {
    __builtin_amdgcn_global_load_lds((glb_u32*)g, (lds_u32*)l, 16, 0, 0);
}

// ---------------------------------------------------------------------------
// LayerNorm: one block per token, 256 threads, 3 elems/thread. fp32 in, fp16 out.
// ---------------------------------------------------------------------------
__global__ __launch_bounds__(256) void ln_kernel(const float* __restrict__ x,
                                                 const float* __restrict__ g,
                                                 const float* __restrict__ b,
                                                 _Float16* __restrict__ out) {
    const int t = blockIdx.x;
    const float* xp = x + (size_t)t * DIM;
    float v[3];
    float s = 0.f, ss = 0.f;
#pragma unroll
    for (int u = 0; u < 3; ++u) {
        v[u] = xp[threadIdx.x + 256 * u];
        s += v[u];
        ss += v[u] * v[u];
    }
#pragma unroll
    for (int m = 1; m < 64; m <<= 1) {
        s  += __shfl_xor(s, m);
        ss += __shfl_xor(ss, m);
    }
    __shared__ float rs[4], rss[4];
    const int wave = threadIdx.x >> 6;
    if ((threadIdx.x & 63) == 0) { rs[wave] = s; rss[wave] = ss; }
    __syncthreads();
    s  = rs[0] + rs[1] + rs[2] + rs[3];
    ss = rss[0] + rss[1] + rss[2] + rss[3];
    const float mu  = s * (1.0f / DIM);
    const float var = ss * (1.0f / DIM) - mu * mu;
    const float rst = 1.0f / sqrtf(var + 1e-5f);
    _Float16* op = out + (size_t)t * DIM;
#pragma unroll
    for (int u = 0; u < 3; ++u) {
        const int c = threadIdx.x + 256 * u;
        op[c] = (_Float16)((v[u] - mu) * rst * g[c] + b[c]);
    }
}

// ---------------------------------------------------------------------------
// fp32 -> fp16 cast (weights), 4 elems/thread
// ---------------------------------------------------------------------------
__global__ __launch_bounds__(256) void cast_kernel(const float* __restrict__ in,
                                                   _Float16* __restrict__ out, int n) {
    const int i = (blockIdx.x * 256 + threadIdx.x) * 4;
    if (i < n) {
        const float4 v = *(const float4*)(in + i);
        f16x4 o;
        o[0] = (_Float16)v.x; o[1] = (_Float16)v.y;
        o[2] = (_Float16)v.z; o[3] = (_Float16)v.w;
        *(f16x4*)(out + i) = o;
    }
}

// ---------------------------------------------------------------------------
// MFMA fp16 GEMM: C[M,N] = A[M,K] @ B[N,K]^T (+bias, +epilogue), fp32 accum.
// BM=BN=128, BK=32, 256 threads = 4 waves (2x2), 64x64 per wave.
// K-slot swizzle applied on the GLOBAL source; LDS dest linear (rule 21).
// EPI: 0 = +bias ; 1 = +bias +residual(fp32) ; 2 = gelu(+bias) exact
// ---------------------------------------------------------------------------
template <int EPI, typename OUT_T>
__global__ __launch_bounds__(256) void gemm_f16(const _Float16* __restrict__ A,
                                                const _Float16* __restrict__ Bw,
                                                const float* __restrict__ bias,
                                                const float* __restrict__ res,
                                                OUT_T* __restrict__ C,
                                                int M, int N, int K) {
    __shared__ _Float16 As[2][128 * 32];
    __shared__ _Float16 Bs[2][128 * 32];

    const int tid  = threadIdx.x;
    const int lane = tid & 63;
    const int wave = tid >> 6;
    const int wr = wave >> 1;
    const int wc = wave & 1;
    const int n0 = blockIdx.x * 128;
    const int m0 = blockIdx.y * 128;

    const int sr = tid >> 2;           // staging row 0..63
    const int sp = tid & 3;            // staging 16B slot 0..3

    f32x4 acc[4][4] = {};

    auto stage = [&](int buf, int k0) {
#pragma unroll
        for (int h = 0; h < 2; ++h) {
            const int r  = sr + h * 64;
            const int kc = sp ^ ((r >> 1) & 3);
            const size_t goff = (size_t)r * K + k0 + kc * 8;
            gload16(A  + (size_t)m0 * K + goff, &As[buf][tid * 8 + h * 2048]);
            gload16(Bw + (size_t)n0 * K + goff, &Bs[buf][tid * 8 + h * 2048]);
        }
    };

    auto compute = [&](int buf) {
        f16x8 a[4], b[4];
#pragma unroll
        for (int m = 0; m < 4; ++m) {
            const int row = wr * 64 + m * 16 + (lane & 15);
            const int p   = (lane >> 4) ^ ((row >> 1) & 3);
            a[m] = *(const f16x8*)&As[buf][row * 32 + p * 8];
        }
#pragma unroll
        for (int n = 0; n < 4; ++n) {
            const int row = wc * 64 + n * 16 + (lane & 15);
            const int p   = (lane >> 4) ^ ((row >> 1) & 3);
            b[n] = *(const f16x8*)&Bs[buf][row * 32 + p * 8];
        }
#pragma unroll
        for (int m = 0; m < 4; ++m)
#pragma unroll
            for (int n = 0; n < 4; ++n)
                acc[m][n] = __builtin_amdgcn_mfma_f32_16x16x32_f16(a[m], b[n], acc[m][n], 0, 0, 0);
    };

    const int NT = K / 32;
    stage(0, 0);
    __syncthreads();
    int cur = 0;
    for (int t = 0; t < NT; ++t) {
        if (t + 1 < NT) stage(cur ^ 1, (t + 1) * 32);
        compute(cur);
        __syncthreads();
        cur ^= 1;
    }

    const int col0 = n0 + wc * 64 + (lane & 15);
#pragma unroll
    for (int m = 0; m < 4; ++m) {
#pragma unroll
        for (int j = 0; j < 4; ++j) {
            const size_t row = (size_t)(m0 + wr * 64 + m * 16 + (lane >> 4) * 4 + j);
#pragma unroll
            for (int n = 0; n < 4; ++n) {
                const int col = col0 + n * 16;
                float c = acc[m][n][j] + bias[col];
                if (EPI == 2) c = 0.5f * c * (1.0f + erff(c * 0.70710678118f));
                if (EPI == 1) c += res[row * N + col];
                C[row * N + col] = (OUT_T)c;
            }
        }
    }
}

// ---------------------------------------------------------------------------
// MFMA flash attention, SWAPPED QK^T structure.
// Block = 256 thr (4 waves) per (64 q-rows, head, batch); wave w owns 16 q-rows.
// S^T = mfma(A=K, B=Q): lane (g,c) holds S[q=c][key=kb*16+g*4+j] -> softmax is
// lane-local + 2 shfl; P packs straight into the PV A-frag in registers (no
// P round-trip). K staged via global_load_lds with chunk-XOR (source-permuted,
// rule 21): phys chunk p holds global chunk p^(key&7); A-frag reads conflict-
// free. V staged transposed Vt[d][key] (chunk swizzle pc=(key>>3)^(d>>3));
// PV B-frag = 2x ds_read_b64 runs matching the packed P key order
// slot(g,e) <-> key 32kk+16(e>>2)+4g+(e&3).
// ---------------------------------------------------------------------------
__global__ __launch_bounds__(256) void attn_kernel(const _Float16* __restrict__ qkv,
                                                   _Float16* __restrict__ out) {
    __shared__ _Float16 K_lds[64 * 64];     // [key][64] chunk-XOR swizzled
    __shared__ _Float16 Vt[64 * 72];        // [d][72] transposed, chunk swizzled

    const int q0 = blockIdx.x * 64;
    const int h  = blockIdx.y;
    const int b  = blockIdx.z;
    const float SCALE2 = 0.05205879570f;    // 1/sqrt(768) * log2(e)

    const int tid  = threadIdx.x;
    const int lane = tid & 63;
    const int w    = tid >> 6;
    const int g    = lane >> 4;             // group 0..3
    const int c    = lane & 15;             // col within 16 (q-row for S^T)

    const int skey = tid >> 3;              // V staging key 0..31
    const int sdc  = tid & 7;               // V staging d-chunk 0..7
    // K staging (gload16): dest = key*64 + (tid&7)*8, key = it*32 + (tid>>3)
    const int kkey = tid >> 3;
    const int kchunk = (tid & 7) ^ ((tid >> 3) & 7);   // global chunk for phys slot

    const size_t base = (size_t)b * SEQ * QKVN + (size_t)h * HD;

    // Q fragments (B operand): lane holds Q[q0 + w*16 + c][kk*32 + g*8 .. +8]
    f16x8 aq[2];
#pragma unroll
    for (int kk = 0; kk < 2; ++kk)
        aq[kk] = *(const f16x8*)(qkv + base + (size_t)(q0 + w * 16 + c) * QKVN + kk * 32 + g * 8);

    f32x4 o[4] = {};                        // O[q=g*4+j][d=n*16+c]
    float mrow = -1e30f, lrow = 0.f;        // softmax state for q-row c

    for (int kt = 0; kt < 16; ++kt) {
        const int k0 = kt * 64;
        __syncthreads();                    // prev tile LDS reads done
#pragma unroll
        for (int it = 0; it < 2; ++it) {
            // K: async global->LDS, source-permuted chunk swizzle
            const int key = kkey + it * 32;
            gload16(qkv + base + 768 + (size_t)(k0 + key) * QKVN + kchunk * 8,
                    &K_lds[it * 2048 + tid * 8]);
            // V: register transpose into Vt[d][key] (chunk swizzled)
            const int vkey = skey + it * 32;
            const f16x8 vv = *(const f16x8*)(qkv + base + 1536 + (size_t)(k0 + vkey) * QKVN + sdc * 8);
            const int pc = (vkey >> 3) ^ sdc;
#pragma unroll
            for (int e = 0; e < 8; ++e)
                Vt[(sdc * 8 + e) * 72 + pc * 8 + (vkey & 7)] = vv[e];
        }
        __syncthreads();                    // staging complete (vmcnt+lgkm drained)

        // S^T = mfma(K, Q): s[kb][j] = S[q=c][key = kb*16 + g*4 + j]
        f32x4 s[4] = {};
        __builtin_amdgcn_s_setprio(1);
#pragma unroll
        for (int kb = 0; kb < 4; ++kb) {
#pragma unroll
            for (int kk = 0; kk < 2; ++kk) {
                const f16x8 ak = *(const f16x8*)&K_lds[(kb * 16 + c) * 64 + (((kk * 4 + g) ^ (c & 7)) * 8)];
                s[kb] = __builtin_amdgcn_mfma_f32_16x16x32_f16(ak, aq[kk], s[kb], 0, 0, 0);
            }
        }
        __builtin_amdgcn_s_setprio(0);

        // online softmax for q-row c, fully lane-local + 2 shuffles
        float p[4][4];
        float mx = -1e30f;
#pragma unroll
        for (int kb = 0; kb < 4; ++kb)
#pragma unroll
            for (int j = 0; j < 4; ++j) {
                p[kb][j] = s[kb][j] * SCALE2;
                mx = fmaxf(mx, p[kb][j]);
            }
        mx = fmaxf(mx, __shfl_xor(mx, 16));
        mx = fmaxf(mx, __shfl_xor(mx, 32));
        const float mnew  = fmaxf(mrow, mx);
        const float alpha = exp2f(mrow - mnew);
        float rsum = 0.f;
#pragma unroll
        for (int kb = 0; kb < 4; ++kb)
#pragma unroll
            for (int j = 0; j < 4; ++j) {
                p[kb][j] = exp2f(p[kb][j] - mnew);
                rsum += p[kb][j];
            }
        rsum += __shfl_xor(rsum, 16);
        rsum += __shfl_xor(rsum, 32);
        lrow = lrow * alpha + rsum;
        mrow = mnew;

        // rescale O by this tile's alpha of row g*4+j (broadcast from lane g*4+j)
#pragma unroll
        for (int j = 0; j < 4; ++j) {
            const float aj = __shfl(alpha, g * 4 + j);
#pragma unroll
            for (int n = 0; n < 4; ++n) o[n][j] *= aj;
        }

        // pack P into PV A-frags: slot (g,e) <-> key 32kk + 16(e>>2) + 4g + (e&3)
        f16x8 pa[2];
#pragma unroll
        for (int kk = 0; kk < 2; ++kk)
#pragma unroll
            for (int e = 0; e < 8; ++e)
                pa[kk][e] = (_Float16)p[2 * kk + (e >> 2)][e & 3];

        // O += P @ V : B-frag = two 4-key runs from Vt per (kk,n)
        __builtin_amdgcn_s_setprio(1);
#pragma unroll
        for (int kk = 0; kk < 2; ++kk) {
#pragma unroll
            for (int n = 0; n < 4; ++n) {
                const int d = n * 16 + c;
                const int ch0 = (4 * kk + (g >> 1)) ^ (d >> 3);
                const int ch1 = (4 * kk + 2 + (g >> 1)) ^ (d >> 3);
                union { uint2 r[2]; f16x8 v; } bb;
                bb.r[0] = *(const uint2*)&Vt[d * 72 + ch0 * 8 + (g & 1) * 4];
                bb.r[1] = *(const uint2*)&Vt[d * 72 + ch1 * 8 + (g & 1) * 4];
                o[n] = __builtin_amdgcn_mfma_f32_16x16x32_f16(pa[kk], bb.v, o[n], 0, 0, 0);
            }
        }
        __builtin_amdgcn_s_setprio(0);
    }

    // write O / l  (1/l broadcast from lane g*4+j)
#pragma unroll
    for (int j = 0; j < 4; ++j) {
        const float linv = 1.0f / __shfl(lrow, g * 4 + j);
        const size_t row = (size_t)(b * SEQ + q0 + w * 16 + g * 4 + j);
#pragma unroll
        for (int n = 0; n < 4; ++n)
            out[row * DIM + h * HD + n * 16 + c] = (_Float16)(o[n][j] * linv);
    }
}

// ---------------------------------------------------------------------------
// Launch
// ---------------------------------------------------------------------------
extern "C" void kernel_launch(void* const* d_in, const int* in_sizes, int n_in,
                              void* d_out, int out_size, void* d_ws, size_t ws_size,
                              hipStream_t stream) {
    const float* x     = (const float*)d_in[0];
    const float* ln_g  = (const float*)d_in[1];
    const float* ln_b  = (const float*)d_in[2];
    const float* w_qkv = (const float*)d_in[3];
    const float* b_qkv = (const float*)d_in[4];
    const float* w_out = (const float*)d_in[5];
    const float* b_out = (const float*)d_in[6];
    const float* w_fc1 = (const float*)d_in[7];
    const float* b_fc1 = (const float*)d_in[8];
    const float* w_fc2 = (const float*)d_in[9];
    const float* b_fc2 = (const float*)d_in[10];
    float* out = (float*)d_out;

    // Workspace layout (bytes):
    //   wq16   @ 0          : 3,538,944
    //   wo16   @ 3,538,944  : 1,179,648
    //   wf1_16 @ 4,718,592  : 4,718,592
    //   wf2_16 @ 9,437,184  : 4,718,592
    //   ln16   @ 14,155,776 : 25,165,824
    //   qkv16  @ 39,321,600 : 75,497,472
    //   attn16 @114,819,072 : 25,165,824
    //   h16    @ 39,321,600 : 100,663,296 (overlaps qkv16+attn16; both dead by FC1)
    char* ws = (char*)d_ws;
    _Float16* wq16   = (_Float16*)(ws);
    _Float16* wo16   = (_Float16*)(ws + 3538944);
    _Float16* wf1_16 = (_Float16*)(ws + 4718592);
    _Float16* wf2_16 = (_Float16*)(ws + 9437184);
    _Float16* ln16   = (_Float16*)(ws + 14155776);
    _Float16* qkv16  = (_Float16*)(ws + 39321600);
    _Float16* attn16 = (_Float16*)(ws + 114819072);
    _Float16* h16    = qkv16;

    // weight casts (fp32 -> fp16)
    cast_kernel<<<(QKVN * DIM) / 1024, 256, 0, stream>>>(w_qkv, wq16, QKVN * DIM);
    cast_kernel<<<(DIM * DIM) / 1024, 256, 0, stream>>>(w_out, wo16, DIM * DIM);
    cast_kernel<<<(HMLP * DIM) / 1024, 256, 0, stream>>>(w_fc1, wf1_16, HMLP * DIM);
    cast_kernel<<<(DIM * HMLP) / 1024, 256, 0, stream>>>(w_fc2, wf2_16, DIM * HMLP);

    // 1. ln1 = layernorm(x) -> fp16
    ln_kernel<<<NTOK, 256, 0, stream>>>(x, ln_g, ln_b, ln16);
    // 2. qkv = ln1 @ w_qkv^T + b_qkv -> fp16
    gemm_f16<0, _Float16><<<dim3(QKVN / 128, NTOK / 128), 256, 0, stream>>>(
        ln16, wq16, b_qkv, nullptr, qkv16, NTOK, QKVN, DIM);
    // 3. attention (swapped-QK^T MFMA flash) -> fp16
    attn_kernel<<<dim3(SEQ / 64, HEADS, NB), 256, 0, stream>>>(qkv16, attn16);
    // 4. x1 = x + attn @ w_out^T + b_out -> d_out (fp32)
    gemm_f16<1, float><<<dim3(DIM / 128, NTOK / 128), 256, 0, stream>>>(
        attn16, wo16, b_out, x, out, NTOK, DIM, DIM);
    // 5. ln2 = layernorm(x1) -> fp16
    ln_kernel<<<NTOK, 256, 0, stream>>>(out, ln_g, ln_b, ln16);
    // 6. h = gelu(ln2 @ w_fc1^T + b_fc1) -> fp16
    gemm_f16<2, _Float16><<<dim3(HMLP / 128, NTOK / 128), 256, 0, stream>>>(
        ln16, wf1_16, b_fc1, nullptr, h16, NTOK, HMLP, DIM);
    // 7. out = x1 + h @ w_fc2^T + b_fc2 -> d_out (fp32)
    gemm_f16<1, float><<<dim3(DIM / 128, NTOK / 128), 256, 0, stream>>>(
        h16, wf2_16, b_fc2, out, out, NTOK, DIM, HMLP);
}

// Round 8
// 667.136 us; speedup vs baseline: 6.1596x; 1.0574x over previous
//
#include <hip/hip_runtime.h>
#include <math.h>

// Problem dims (fixed by reference)
#define DIM    768
#define NB     16
#define SEQ    1024
#define NTOK   (NB*SEQ)        // 16384
#define HEADS  12
#define HD     64
#define HMLP   3072
#define QKVN   2304

typedef _Float16 f16x8 __attribute__((ext_vector_type(8)));
typedef _Float16 f16x4 __attribute__((ext_vector_type(4)));
typedef float    f32x4 __attribute__((ext_vector_type(4)));

typedef __attribute__((address_space(3))) unsigned int       lds_u32;
typedef __attribute__((address_space(1))) const unsigned int glb_u32;

// async global->LDS, 16 bytes per lane. LDS dest must be linear in lane order.
__device__ __forceinline__ void gload16(const _Float16* g, _Float16* l) {
    __builtin_amdgcn_global_load_lds((glb_u32*)g, (lds_u32*)l, 16, 0, 0);
}

// ---------------------------------------------------------------------------
// LayerNorm: one block per token, 256 threads, 3 elems/thread. fp32 in, fp16 out.
// ---------------------------------------------------------------------------
__global__ __launch_bounds__(256) void ln_kernel(const float* __restrict__ x,
                                                 const float* __restrict__ g,
                                                 const float* __restrict__ b,
                                                 _Float16* __restrict__ out) {
    const int t = blockIdx.x;
    const float* xp = x + (size_t)t * DIM;
    float v[3];
    float s = 0.f, ss = 0.f;
#pragma unroll
    for (int u = 0; u < 3; ++u) {
        v[u] = xp[threadIdx.x + 256 * u];
        s += v[u];
        ss += v[u] * v[u];
    }
#pragma unroll
    for (int m = 1; m < 64; m <<= 1) {
        s  += __shfl_xor(s, m);
        ss += __shfl_xor(ss, m);
    }
    __shared__ float rs[4], rss[4];
    const int wave = threadIdx.x >> 6;
    if ((threadIdx.x & 63) == 0) { rs[wave] = s; rss[wave] = ss; }
    __syncthreads();
    s  = rs[0] + rs[1] + rs[2] + rs[3];
    ss = rss[0] + rss[1] + rss[2] + rss[3];
    const float mu  = s * (1.0f / DIM);
    const float var = ss * (1.0f / DIM) - mu * mu;
    const float rst = 1.0f / sqrtf(var + 1e-5f);
    _Float16* op = out + (size_t)t * DIM;
#pragma unroll
    for (int u = 0; u < 3; ++u) {
        const int c = threadIdx.x + 256 * u;
        op[c] = (_Float16)((v[u] - mu) * rst * g[c] + b[c]);
    }
}

// ---------------------------------------------------------------------------
// fp32 -> fp16 cast (weights), 4 elems/thread
// ---------------------------------------------------------------------------
__global__ __launch_bounds__(256) void cast_kernel(const float* __restrict__ in,
                                                   _Float16* __restrict__ out, int n) {
    const int i = (blockIdx.x * 256 + threadIdx.x) * 4;
    if (i < n) {
        const float4 v = *(const float4*)(in + i);
        f16x4 o;
        o[0] = (_Float16)v.x; o[1] = (_Float16)v.y;
        o[2] = (_Float16)v.z; o[3] = (_Float16)v.w;
        *(f16x4*)(out + i) = o;
    }
}

// ---------------------------------------------------------------------------
// MFMA fp16 GEMM: C[M,N] = A[M,K] @ B[N,K]^T (+bias, +epilogue), fp32 accum.
// BM=BN=128, BK=32, 256 threads = 4 waves (2x2), 64x64 per wave.
// TRIPLE-buffered LDS, counted s_waitcnt vmcnt(4) (tile t+1 stays in flight
// across the raw s_barrier — T4), stage(t+2) issued after the barrier
// (buffer (t+2)%3 == (t-1)%3 is provably dead there). XCD-aware bijective
// block swizzle (T1; all grids have nwg%8==0). K-slot swizzle on the GLOBAL
// source; LDS dest linear (rule 21).
// EPI: 0 = +bias ; 1 = +bias +residual(fp32) ; 2 = gelu(+bias) exact
// ---------------------------------------------------------------------------
template <int EPI, typename OUT_T>
__global__ __launch_bounds__(256) void gemm_f16(const _Float16* __restrict__ A,
                                                const _Float16* __restrict__ Bw,
                                                const float* __restrict__ bias,
                                                const float* __restrict__ res,
                                                OUT_T* __restrict__ C,
                                                int M, int N, int K) {
    __shared__ _Float16 As[3][128 * 32];
    __shared__ _Float16 Bs[3][128 * 32];

    const int tid  = threadIdx.x;
    const int lane = tid & 63;
    const int wave = tid >> 6;
    const int wr = wave >> 1;
    const int wc = wave & 1;

    // XCD-aware bijective swizzle (nwg multiple of 8): hw block 'orig' on
    // XCD orig%8 computes tile 'wgid'; each XCD gets a contiguous tile chunk.
    const int nwg  = gridDim.x * gridDim.y;
    const int orig = blockIdx.y * gridDim.x + blockIdx.x;
    const int wgid = (orig & 7) * (nwg >> 3) + (orig >> 3);
    const int n0 = (wgid % gridDim.x) * 128;
    const int m0 = (wgid / gridDim.x) * 128;

    const int sr = tid >> 2;           // staging row 0..63
    const int sp = tid & 3;            // staging 16B slot 0..3

    f32x4 acc[4][4] = {};

    auto stage = [&](int buf, int k0) {
#pragma unroll
        for (int h = 0; h < 2; ++h) {
            const int r  = sr + h * 64;
            const int kc = sp ^ ((r >> 1) & 3);
            const size_t goff = (size_t)r * K + k0 + kc * 8;
            gload16(A  + (size_t)m0 * K + goff, &As[buf][tid * 8 + h * 2048]);
            gload16(Bw + (size_t)n0 * K + goff, &Bs[buf][tid * 8 + h * 2048]);
        }
    };

    auto compute = [&](int buf) {
        f16x8 a[4], b[4];
#pragma unroll
        for (int m = 0; m < 4; ++m) {
            const int row = wr * 64 + m * 16 + (lane & 15);
            const int p   = (lane >> 4) ^ ((row >> 1) & 3);
            a[m] = *(const f16x8*)&As[buf][row * 32 + p * 8];
        }
#pragma unroll
        for (int n = 0; n < 4; ++n) {
            const int row = wc * 64 + n * 16 + (lane & 15);
            const int p   = (lane >> 4) ^ ((row >> 1) & 3);
            b[n] = *(const f16x8*)&Bs[buf][row * 32 + p * 8];
        }
#pragma unroll
        for (int m = 0; m < 4; ++m)
#pragma unroll
            for (int n = 0; n < 4; ++n)
                acc[m][n] = __builtin_amdgcn_mfma_f32_16x16x32_f16(a[m], b[n], acc[m][n], 0, 0, 0);
    };

    const int NT = K / 32;             // 24 or 96 (>= 3 always here)
    stage(0, 0);
    stage(1, 32);
    int cur = 0;
    for (int t = 0; t < NT; ++t) {
        // tile t ready; keep tile t+1 (4 loads/wave) in flight — never drain
        // to 0 mid-loop. Each wave waits for its OWN loads before the barrier,
        // so barrier-release implies all waves' tile-t DMA has landed.
        if (t + 1 < NT) asm volatile("s_waitcnt vmcnt(4)");
        else            asm volatile("s_waitcnt vmcnt(0)");
        __builtin_amdgcn_sched_barrier(0);
        __builtin_amdgcn_s_barrier();
        __builtin_amdgcn_sched_barrier(0);
        int nxt = cur + 2; if (nxt >= 3) nxt -= 3;
        if (t + 2 < NT) stage(nxt, (t + 2) * 32);
        compute(cur);
        ++cur; if (cur == 3) cur = 0;
    }

    const int col0 = n0 + wc * 64 + (lane & 15);
#pragma unroll
    for (int m = 0; m < 4; ++m) {
#pragma unroll
        for (int j = 0; j < 4; ++j) {
            const size_t row = (size_t)(m0 + wr * 64 + m * 16 + (lane >> 4) * 4 + j);
#pragma unroll
            for (int n = 0; n < 4; ++n) {
                const int col = col0 + n * 16;
                float c = acc[m][n][j] + bias[col];
                if (EPI == 2) c = 0.5f * c * (1.0f + erff(c * 0.70710678118f));
                if (EPI == 1) c += res[row * N + col];
                C[row * N + col] = (OUT_T)c;
            }
        }
    }
}

// ---------------------------------------------------------------------------
// MFMA flash attention, SWAPPED QK^T structure (unchanged from R6, validated).
// ---------------------------------------------------------------------------
__global__ __launch_bounds__(256) void attn_kernel(const _Float16* __restrict__ qkv,
                                                   _Float16* __restrict__ out) {
    __shared__ _Float16 K_lds[64 * 64];     // [key][64] chunk-XOR swizzled
    __shared__ _Float16 Vt[64 * 72];        // [d][72] transposed, chunk swizzled

    const int q0 = blockIdx.x * 64;
    const int h  = blockIdx.y;
    const int b  = blockIdx.z;
    const float SCALE2 = 0.05205879570f;    // 1/sqrt(768) * log2(e)

    const int tid  = threadIdx.x;
    const int lane = tid & 63;
    const int w    = tid >> 6;
    const int g    = lane >> 4;             // group 0..3
    const int c    = lane & 15;             // col within 16 (q-row for S^T)

    const int skey = tid >> 3;              // V staging key 0..31
    const int sdc  = tid & 7;               // V staging d-chunk 0..7
    const int kkey = tid >> 3;
    const int kchunk = (tid & 7) ^ ((tid >> 3) & 7);   // global chunk for phys slot

    const size_t base = (size_t)b * SEQ * QKVN + (size_t)h * HD;

    f16x8 aq[2];
#pragma unroll
    for (int kk = 0; kk < 2; ++kk)
        aq[kk] = *(const f16x8*)(qkv + base + (size_t)(q0 + w * 16 + c) * QKVN + kk * 32 + g * 8);

    f32x4 o[4] = {};                        // O[q=g*4+j][d=n*16+c]
    float mrow = -1e30f, lrow = 0.f;        // softmax state for q-row c

    for (int kt = 0; kt < 16; ++kt) {
        const int k0 = kt * 64;
        __syncthreads();                    // prev tile LDS reads done
#pragma unroll
        for (int it = 0; it < 2; ++it) {
            const int key = kkey + it * 32;
            gload16(qkv + base + 768 + (size_t)(k0 + key) * QKVN + kchunk * 8,
                    &K_lds[it * 2048 + tid * 8]);
            const int vkey = skey + it * 32;
            const f16x8 vv = *(const f16x8*)(qkv + base + 1536 + (size_t)(k0 + vkey) * QKVN + sdc * 8);
            const int pc = (vkey >> 3) ^ sdc;
#pragma unroll
            for (int e = 0; e < 8; ++e)
                Vt[(sdc * 8 + e) * 72 + pc * 8 + (vkey & 7)] = vv[e];
        }
        __syncthreads();                    // staging complete

        f32x4 s[4] = {};
        __builtin_amdgcn_s_setprio(1);
#pragma unroll
        for (int kb = 0; kb < 4; ++kb) {
#pragma unroll
            for (int kk = 0; kk < 2; ++kk) {
                const f16x8 ak = *(const f16x8*)&K_lds[(kb * 16 + c) * 64 + (((kk * 4 + g) ^ (c & 7)) * 8)];
                s[kb] = __builtin_amdgcn_mfma_f32_16x16x32_f16(ak, aq[kk], s[kb], 0, 0, 0);
            }
        }
        __builtin_amdgcn_s_setprio(0);

        float p[4][4];
        float mx = -1e30f;
#pragma unroll
        for (int kb = 0; kb < 4; ++kb)
#pragma unroll
            for (int j = 0; j < 4; ++j) {
                p[kb][j] = s[kb][j] * SCALE2;
                mx = fmaxf(mx, p[kb][j]);
            }
        mx = fmaxf(mx, __shfl_xor(mx, 16));
        mx = fmaxf(mx, __shfl_xor(mx, 32));
        const float mnew  = fmaxf(mrow, mx);
        const float alpha = exp2f(mrow - mnew);
        float rsum = 0.f;
#pragma unroll
        for (int kb = 0; kb < 4; ++kb)
#pragma unroll
            for (int j = 0; j < 4; ++j) {
                p[kb][j] = exp2f(p[kb][j] - mnew);
                rsum += p[kb][j];
            }
        rsum += __shfl_xor(rsum, 16);
        rsum += __shfl_xor(rsum, 32);
        lrow = lrow * alpha + rsum;
        mrow = mnew;

#pragma unroll
        for (int j = 0; j < 4; ++j) {
            const float aj = __shfl(alpha, g * 4 + j);
#pragma unroll
            for (int n = 0; n < 4; ++n) o[n][j] *= aj;
        }

        f16x8 pa[2];
#pragma unroll
        for (int kk = 0; kk < 2; ++kk)
#pragma unroll
            for (int e = 0; e < 8; ++e)
                pa[kk][e] = (_Float16)p[2 * kk + (e >> 2)][e & 3];

        __builtin_amdgcn_s_setprio(1);
#pragma unroll
        for (int kk = 0; kk < 2; ++kk) {
#pragma unroll
            for (int n = 0; n < 4; ++n) {
                const int d = n * 16 + c;
                const int ch0 = (4 * kk + (g >> 1)) ^ (d >> 3);
                const int ch1 = (4 * kk + 2 + (g >> 1)) ^ (d >> 3);
                union { uint2 r[2]; f16x8 v; } bb;
                bb.r[0] = *(const uint2*)&Vt[d * 72 + ch0 * 8 + (g & 1) * 4];
                bb.r[1] = *(const uint2*)&Vt[d * 72 + ch1 * 8 + (g & 1) * 4];
                o[n] = __builtin_amdgcn_mfma_f32_16x16x32_f16(pa[kk], bb.v, o[n], 0, 0, 0);
            }
        }
        __builtin_amdgcn_s_setprio(0);
    }

#pragma unroll
    for (int j = 0; j < 4; ++j) {
        const float linv = 1.0f / __shfl(lrow, g * 4 + j);
        const size_t row = (size_t)(b * SEQ + q0 + w * 16 + g * 4 + j);
#pragma unroll
        for (int n = 0; n < 4; ++n)
            out[row * DIM + h * HD + n * 16 + c] = (_Float16)(o[n][j] * linv);
    }
}

// ---------------------------------------------------------------------------
// Launch
// ---------------------------------------------------------------------------
extern "C" void kernel_launch(void* const* d_in, const int* in_sizes, int n_in,
                              void* d_out, int out_size, void* d_ws, size_t ws_size,
                              hipStream_t stream) {
    const float* x     = (const float*)d_in[0];
    const float* ln_g  = (const float*)d_in[1];
    const float* ln_b  = (const float*)d_in[2];
    const float* w_qkv = (const float*)d_in[3];
    const float* b_qkv = (const float*)d_in[4];
    const float* w_out = (const float*)d_in[5];
    const float* b_out = (const float*)d_in[6];
    const float* w_fc1 = (const float*)d_in[7];
    const float* b_fc1 = (const float*)d_in[8];
    const float* w_fc2 = (const float*)d_in[9];
    const float* b_fc2 = (const float*)d_in[10];
    float* out = (float*)d_out;

    // Workspace layout (bytes):
    //   wq16   @ 0          : 3,538,944
    //   wo16   @ 3,538,944  : 1,179,648
    //   wf1_16 @ 4,718,592  : 4,718,592
    //   wf2_16 @ 9,437,184  : 4,718,592
    //   ln16   @ 14,155,776 : 25,165,824
    //   qkv16  @ 39,321,600 : 75,497,472
    //   attn16 @114,819,072 : 25,165,824
    //   h16    @ 39,321,600 : 100,663,296 (overlaps qkv16+attn16; both dead by FC1)
    char* ws = (char*)d_ws;
    _Float16* wq16   = (_Float16*)(ws);
    _Float16* wo16   = (_Float16*)(ws + 3538944);
    _Float16* wf1_16 = (_Float16*)(ws + 4718592);
    _Float16* wf2_16 = (_Float16*)(ws + 9437184);
    _Float16* ln16   = (_Float16*)(ws + 14155776);
    _Float16* qkv16  = (_Float16*)(ws + 39321600);
    _Float16* attn16 = (_Float16*)(ws + 114819072);
    _Float16* h16    = qkv16;

    // weight casts (fp32 -> fp16)
    cast_kernel<<<(QKVN * DIM) / 1024, 256, 0, stream>>>(w_qkv, wq16, QKVN * DIM);
    cast_kernel<<<(DIM * DIM) / 1024, 256, 0, stream>>>(w_out, wo16, DIM * DIM);
    cast_kernel<<<(HMLP * DIM) / 1024, 256, 0, stream>>>(w_fc1, wf1_16, HMLP * DIM);
    cast_kernel<<<(DIM * HMLP) / 1024, 256, 0, stream>>>(w_fc2, wf2_16, DIM * HMLP);

    // 1. ln1 = layernorm(x) -> fp16
    ln_kernel<<<NTOK, 256, 0, stream>>>(x, ln_g, ln_b, ln16);
    // 2. qkv = ln1 @ w_qkv^T + b_qkv -> fp16   (grid 18x128 = 2304 blocks)
    gemm_f16<0, _Float16><<<dim3(QKVN / 128, NTOK / 128), 256, 0, stream>>>(
        ln16, wq16, b_qkv, nullptr, qkv16, NTOK, QKVN, DIM);
    // 3. attention (swapped-QK^T MFMA flash) -> fp16
    attn_kernel<<<dim3(SEQ / 64, HEADS, NB), 256, 0, stream>>>(qkv16, attn16);
    // 4. x1 = x + attn @ w_out^T + b_out -> d_out (fp32)   (grid 6x128)
    gemm_f16<1, float><<<dim3(DIM / 128, NTOK / 128), 256, 0, stream>>>(
        attn16, wo16, b_out, x, out, NTOK, DIM, DIM);
    // 5. ln2 = layernorm(x1) -> fp16
    ln_kernel<<<NTOK, 256, 0, stream>>>(out, ln_g, ln_b, ln16);
    // 6. h = gelu(ln2 @ w_fc1^T + b_fc1) -> fp16   (grid 24x128)
    gemm_f16<2, _Float16><<<dim3(HMLP / 128, NTOK / 128), 256, 0, stream>>>(
        ln16, wf1_16, b_fc1, nullptr, h16, NTOK, HMLP, DIM);
    // 7. out = x1 + h @ w_fc2^T + b_fc2 -> d_out (fp32)   (grid 6x128)
    gemm_f16<1, float><<<dim3(DIM / 128, NTOK / 128), 256, 0, stream>>>(
        h16, wf2_16, b_fc2, out, out, NTOK, DIM, HMLP);
}

// Round 12
// 656.985 us; speedup vs baseline: 6.2548x; 1.0155x over previous
//
#include <hip/hip_runtime.h>
#include <math.h>

// Problem dims (fixed by reference)
#define DIM    768
#define NB     16
#define SEQ    1024
#define NTOK   (NB*SEQ)        // 16384
#define HEADS  12
#define HD     64
#define HMLP   3072
#define QKVN   2304

typedef _Float16 f16x8 __attribute__((ext_vector_type(8)));
typedef _Float16 f16x4 __attribute__((ext_vector_type(4)));
typedef float    f32x4 __attribute__((ext_vector_type(4)));

typedef __attribute__((address_space(3))) unsigned int       lds_u32;
typedef __attribute__((address_space(1))) const unsigned int glb_u32;

// async global->LDS, 16 bytes per lane. LDS dest must be linear in lane order.
__device__ __forceinline__ void gload16(const _Float16* g, _Float16* l) {
    __builtin_amdgcn_global_load_lds((glb_u32*)g, (lds_u32*)l, 16, 0, 0);
}

// ---------------------------------------------------------------------------
// LayerNorm: one block per token, 256 threads, 3 elems/thread. fp32 in, fp16 out.
// ---------------------------------------------------------------------------
__global__ __launch_bounds__(256) void ln_kernel(const float* __restrict__ x,
                                                 const float* __restrict__ g,
                                                 const float* __restrict__ b,
                                                 _Float16* __restrict__ out) {
    const int t = blockIdx.x;
    const float* xp = x + (size_t)t * DIM;
    float v[3];
    float s = 0.f, ss = 0.f;
#pragma unroll
    for (int u = 0; u < 3; ++u) {
        v[u] = xp[threadIdx.x + 256 * u];
        s += v[u];
        ss += v[u] * v[u];
    }
#pragma unroll
    for (int m = 1; m < 64; m <<= 1) {
        s  += __shfl_xor(s, m);
        ss += __shfl_xor(ss, m);
    }
    __shared__ float rs[4], rss[4];
    const int wave = threadIdx.x >> 6;
    if ((threadIdx.x & 63) == 0) { rs[wave] = s; rss[wave] = ss; }
    __syncthreads();
    s  = rs[0] + rs[1] + rs[2] + rs[3];
    ss = rss[0] + rss[1] + rss[2] + rss[3];
    const float mu  = s * (1.0f / DIM);
    const float var = ss * (1.0f / DIM) - mu * mu;
    const float rst = 1.0f / sqrtf(var + 1e-5f);
    _Float16* op = out + (size_t)t * DIM;
#pragma unroll
    for (int u = 0; u < 3; ++u) {
        const int c = threadIdx.x + 256 * u;
        op[c] = (_Float16)((v[u] - mu) * rst * g[c] + b[c]);
    }
}

// ---------------------------------------------------------------------------
// fp32 -> fp16 cast (weights), 4 elems/thread
// ---------------------------------------------------------------------------
__global__ __launch_bounds__(256) void cast_kernel(const float* __restrict__ in,
                                                   _Float16* __restrict__ out, int n) {
    const int i = (blockIdx.x * 256 + threadIdx.x) * 4;
    if (i < n) {
        const float4 v = *(const float4*)(in + i);
        f16x4 o;
        o[0] = (_Float16)v.x; o[1] = (_Float16)v.y;
        o[2] = (_Float16)v.z; o[3] = (_Float16)v.w;
        *(f16x4*)(out + i) = o;
    }
}

// ---------------------------------------------------------------------------
// MFMA fp16 GEMM: C[M,N_] = A[M,K_] @ B[N_,K_]^T (+bias, +epilogue), fp32 accum.
// BM=BN=128, BK=32, 256 threads = 4 waves (2x2), 64x64 per wave.
// Triple-buffered pipeline with STATIC buffer addressing: 6 distinct __shared__
// arrays, K-loop unrolled x3 so every LDS offset is compile-time — lets alias
// analysis keep the counted s_waitcnt vmcnt(4) (tile t+1 in flight across the
// barrier) instead of inserting a conservative vmcnt(0) drain (R8 lesson).
// Safety: MFMAs consume all ds_reads of buffer B before the wave reaches the
// next barrier, so the stage overwriting B (2 barriers later) cannot race.
// XCD-aware bijective block swizzle (nwg%8==0). K-slot swizzle on the GLOBAL
// source; LDS dest linear (rule 21).
// EPI: 0 = +bias ; 1 = +bias +residual(fp32) ; 2 = gelu(+bias) exact
// ---------------------------------------------------------------------------
template <int EPI, typename OUT_T, int N_, int K_>
__global__ __launch_bounds__(256) void gemm_f16(const _Float16* __restrict__ A,
                                                const _Float16* __restrict__ Bw,
                                                const float* __restrict__ bias,
                                                const float* __restrict__ res,
                                                OUT_T* __restrict__ C) {
    __shared__ _Float16 As0[128 * 32], As1[128 * 32], As2[128 * 32];
    __shared__ _Float16 Bs0[128 * 32], Bs1[128 * 32], Bs2[128 * 32];

    const int tid  = threadIdx.x;
    const int lane = tid & 63;
    const int wave = tid >> 6;
    const int wr = wave >> 1;
    const int wc = wave & 1;

    // XCD-aware bijective swizzle (nwg multiple of 8)
    const int nwg  = gridDim.x * gridDim.y;
    const int orig = blockIdx.y * gridDim.x + blockIdx.x;
    const int wgid = (orig & 7) * (nwg >> 3) + (orig >> 3);
    const int n0 = (wgid % gridDim.x) * 128;
    const int m0 = (wgid / gridDim.x) * 128;

    const int sr = tid >> 2;           // staging row 0..63
    const int sp = tid & 3;            // staging 16B slot 0..3

    f32x4 acc[4][4] = {};

    const int NT = K_ / 32;            // 24 or 96 — divisible by 3

#define STAGE(SA, SB, k0)                                                     \
    do {                                                                      \
        _Pragma("unroll")                                                     \
        for (int h = 0; h < 2; ++h) {                                         \
            const int r  = sr + h * 64;                                       \
            const int kc = sp ^ ((r >> 1) & 3);                               \
            const size_t goff = (size_t)r * K_ + (k0) + kc * 8;               \
            gload16(A  + (size_t)m0 * K_ + goff, &SA[tid * 8 + h * 2048]);    \
            gload16(Bw + (size_t)n0 * K_ + goff, &SB[tid * 8 + h * 2048]);    \
        }                                                                     \
    } while (0)

#define COMPUTE(CA, CB)                                                       \
    do {                                                                      \
        f16x8 a[4], b[4];                                                     \
        _Pragma("unroll")                                                     \
        for (int m = 0; m < 4; ++m) {                                         \
            const int row = wr * 64 + m * 16 + (lane & 15);                   \
            const int p   = (lane >> 4) ^ ((row >> 1) & 3);                   \
            a[m] = *(const f16x8*)&CA[row * 32 + p * 8];                      \
        }                                                                     \
        _Pragma("unroll")                                                     \
        for (int n = 0; n < 4; ++n) {                                         \
            const int row = wc * 64 + n * 16 + (lane & 15);                   \
            const int p   = (lane >> 4) ^ ((row >> 1) & 3);                   \
            b[n] = *(const f16x8*)&CB[row * 32 + p * 8];                      \
        }                                                                     \
        _Pragma("unroll")                                                     \
        for (int m = 0; m < 4; ++m)                                           \
            _Pragma("unroll")                                                 \
            for (int n = 0; n < 4; ++n)                                       \
                acc[m][n] = __builtin_amdgcn_mfma_f32_16x16x32_f16(           \
                    a[m], b[n], acc[m][n], 0, 0, 0);                          \
    } while (0)

#define STEP(CA, CB, SA, SB)                                                  \
    do {                                                                      \
        if (t + 1 < NT) asm volatile("s_waitcnt vmcnt(4)");                   \
        else            asm volatile("s_waitcnt vmcnt(0)");                   \
        __builtin_amdgcn_sched_barrier(0);                                    \
        __builtin_amdgcn_s_barrier();                                         \
        __builtin_amdgcn_sched_barrier(0);                                    \
        if (t + 2 < NT) STAGE(SA, SB, (t + 2) * 32);                          \
        COMPUTE(CA, CB);                                                      \
        ++t;                                                                  \
    } while (0)

    STAGE(As0, Bs0, 0);
    STAGE(As1, Bs1, 32);
    int t = 0;
    for (int tt = 0; tt < NT / 3; ++tt) {
        STEP(As0, Bs0, As2, Bs2);
        STEP(As1, Bs1, As0, Bs0);
        STEP(As2, Bs2, As1, Bs1);
    }
#undef STEP
#undef COMPUTE
#undef STAGE

    const int col0 = n0 + wc * 64 + (lane & 15);
#pragma unroll
    for (int m = 0; m < 4; ++m) {
#pragma unroll
        for (int j = 0; j < 4; ++j) {
            const size_t row = (size_t)(m0 + wr * 64 + m * 16 + (lane >> 4) * 4 + j);
#pragma unroll
            for (int n = 0; n < 4; ++n) {
                const int col = col0 + n * 16;
                float c = acc[m][n][j] + bias[col];
                if (EPI == 2) c = 0.5f * c * (1.0f + erff(c * 0.70710678118f));
                if (EPI == 1) c += res[row * N_ + col];
                C[row * N_ + col] = (OUT_T)c;
            }
        }
    }
}

// ---------------------------------------------------------------------------
// MFMA flash attention, SWAPPED QK^T structure (unchanged — validated R6/R7).
// ---------------------------------------------------------------------------
__global__ __launch_bounds__(256) void attn_kernel(const _Float16* __restrict__ qkv,
                                                   _Float16* __restrict__ out) {
    __shared__ _Float16 K_lds[64 * 64];     // [key][64] chunk-XOR swizzled
    __shared__ _Float16 Vt[64 * 72];        // [d][72] transposed, chunk swizzled

    const int q0 = blockIdx.x * 64;
    const int h  = blockIdx.y;
    const int b  = blockIdx.z;
    const float SCALE2 = 0.05205879570f;    // 1/sqrt(768) * log2(e)

    const int tid  = threadIdx.x;
    const int lane = tid & 63;
    const int w    = tid >> 6;
    const int g    = lane >> 4;             // group 0..3
    const int c    = lane & 15;             // col within 16 (q-row for S^T)

    const int skey = tid >> 3;              // V staging key 0..31
    const int sdc  = tid & 7;               // V staging d-chunk 0..7
    const int kkey = tid >> 3;
    const int kchunk = (tid & 7) ^ ((tid >> 3) & 7);   // global chunk for phys slot

    const size_t base = (size_t)b * SEQ * QKVN + (size_t)h * HD;

    f16x8 aq[2];
#pragma unroll
    for (int kk = 0; kk < 2; ++kk)
        aq[kk] = *(const f16x8*)(qkv + base + (size_t)(q0 + w * 16 + c) * QKVN + kk * 32 + g * 8);

    f32x4 o[4] = {};                        // O[q=g*4+j][d=n*16+c]
    float mrow = -1e30f, lrow = 0.f;        // softmax state for q-row c

    for (int kt = 0; kt < 16; ++kt) {
        const int k0 = kt * 64;
        __syncthreads();                    // prev tile LDS reads done
#pragma unroll
        for (int it = 0; it < 2; ++it) {
            const int key = kkey + it * 32;
            gload16(qkv + base + 768 + (size_t)(k0 + key) * QKVN + kchunk * 8,
                    &K_lds[it * 2048 + tid * 8]);
            const int vkey = skey + it * 32;
            const f16x8 vv = *(const f16x8*)(qkv + base + 1536 + (size_t)(k0 + vkey) * QKVN + sdc * 8);
            const int pc = (vkey >> 3) ^ sdc;
#pragma unroll
            for (int e = 0; e < 8; ++e)
                Vt[(sdc * 8 + e) * 72 + pc * 8 + (vkey & 7)] = vv[e];
        }
        __syncthreads();                    // staging complete

        f32x4 s[4] = {};
        __builtin_amdgcn_s_setprio(1);
#pragma unroll
        for (int kb = 0; kb < 4; ++kb) {
#pragma unroll
            for (int kk = 0; kk < 2; ++kk) {
                const f16x8 ak = *(const f16x8*)&K_lds[(kb * 16 + c) * 64 + (((kk * 4 + g) ^ (c & 7)) * 8)];
                s[kb] = __builtin_amdgcn_mfma_f32_16x16x32_f16(ak, aq[kk], s[kb], 0, 0, 0);
            }
        }
        __builtin_amdgcn_s_setprio(0);

        float p[4][4];
        float mx = -1e30f;
#pragma unroll
        for (int kb = 0; kb < 4; ++kb)
#pragma unroll
            for (int j = 0; j < 4; ++j) {
                p[kb][j] = s[kb][j] * SCALE2;
                mx = fmaxf(mx, p[kb][j]);
            }
        mx = fmaxf(mx, __shfl_xor(mx, 16));
        mx = fmaxf(mx, __shfl_xor(mx, 32));
        const float mnew  = fmaxf(mrow, mx);
        const float alpha = exp2f(mrow - mnew);
        float rsum = 0.f;
#pragma unroll
        for (int kb = 0; kb < 4; ++kb)
#pragma unroll
            for (int j = 0; j < 4; ++j) {
                p[kb][j] = exp2f(p[kb][j] - mnew);
                rsum += p[kb][j];
            }
        rsum += __shfl_xor(rsum, 16);
        rsum += __shfl_xor(rsum, 32);
        lrow = lrow * alpha + rsum;
        mrow = mnew;

#pragma unroll
        for (int j = 0; j < 4; ++j) {
            const float aj = __shfl(alpha, g * 4 + j);
#pragma unroll
            for (int n = 0; n < 4; ++n) o[n][j] *= aj;
        }

        f16x8 pa[2];
#pragma unroll
        for (int kk = 0; kk < 2; ++kk)
#pragma unroll
            for (int e = 0; e < 8; ++e)
                pa[kk][e] = (_Float16)p[2 * kk + (e >> 2)][e & 3];

        __builtin_amdgcn_s_setprio(1);
#pragma unroll
        for (int kk = 0; kk < 2; ++kk) {
#pragma unroll
            for (int n = 0; n < 4; ++n) {
                const int d = n * 16 + c;
                const int ch0 = (4 * kk + (g >> 1)) ^ (d >> 3);
                const int ch1 = (4 * kk + 2 + (g >> 1)) ^ (d >> 3);
                union { uint2 r[2]; f16x8 v; } bb;
                bb.r[0] = *(const uint2*)&Vt[d * 72 + ch0 * 8 + (g & 1) * 4];
                bb.r[1] = *(const uint2*)&Vt[d * 72 + ch1 * 8 + (g & 1) * 4];
                o[n] = __builtin_amdgcn_mfma_f32_16x16x32_f16(pa[kk], bb.v, o[n], 0, 0, 0);
            }
        }
        __builtin_amdgcn_s_setprio(0);
    }

#pragma unroll
    for (int j = 0; j < 4; ++j) {
        const float linv = 1.0f / __shfl(lrow, g * 4 + j);
        const size_t row = (size_t)(b * SEQ + q0 + w * 16 + g * 4 + j);
#pragma unroll
        for (int n = 0; n < 4; ++n)
            out[row * DIM + h * HD + n * 16 + c] = (_Float16)(o[n][j] * linv);
    }
}

// ---------------------------------------------------------------------------
// Launch
// ---------------------------------------------------------------------------
extern "C" void kernel_launch(void* const* d_in, const int* in_sizes, int n_in,
                              void* d_out, int out_size, void* d_ws, size_t ws_size,
                              hipStream_t stream) {
    const float* x     = (const float*)d_in[0];
    const float* ln_g  = (const float*)d_in[1];
    const float* ln_b  = (const float*)d_in[2];
    const float* w_qkv = (const float*)d_in[3];
    const float* b_qkv = (const float*)d_in[4];
    const float* w_out = (const float*)d_in[5];
    const float* b_out = (const float*)d_in[6];
    const float* w_fc1 = (const float*)d_in[7];
    const float* b_fc1 = (const float*)d_in[8];
    const float* w_fc2 = (const float*)d_in[9];
    const float* b_fc2 = (const float*)d_in[10];
    float* out = (float*)d_out;

    // Workspace layout (bytes):
    //   wq16   @ 0          : 3,538,944
    //   wo16   @ 3,538,944  : 1,179,648
    //   wf1_16 @ 4,718,592  : 4,718,592
    //   wf2_16 @ 9,437,184  : 4,718,592
    //   ln16   @ 14,155,776 : 25,165,824
    //   qkv16  @ 39,321,600 : 75,497,472
    //   attn16 @114,819,072 : 25,165,824
    //   h16    @ 39,321,600 : 100,663,296 (overlaps qkv16+attn16; both dead by FC1)
    char* ws = (char*)d_ws;
    _Float16* wq16   = (_Float16*)(ws);
    _Float16* wo16   = (_Float16*)(ws + 3538944);
    _Float16* wf1_16 = (_Float16*)(ws + 4718592);
    _Float16* wf2_16 = (_Float16*)(ws + 9437184);
    _Float16* ln16   = (_Float16*)(ws + 14155776);
    _Float16* qkv16  = (_Float16*)(ws + 39321600);
    _Float16* attn16 = (_Float16*)(ws + 114819072);
    _Float16* h16    = qkv16;

    // weight casts (fp32 -> fp16)
    cast_kernel<<<(QKVN * DIM) / 1024, 256, 0, stream>>>(w_qkv, wq16, QKVN * DIM);
    cast_kernel<<<(DIM * DIM) / 1024, 256, 0, stream>>>(w_out, wo16, DIM * DIM);
    cast_kernel<<<(HMLP * DIM) / 1024, 256, 0, stream>>>(w_fc1, wf1_16, HMLP * DIM);
    cast_kernel<<<(DIM * HMLP) / 1024, 256, 0, stream>>>(w_fc2, wf2_16, DIM * HMLP);

    // 1. ln1 = layernorm(x) -> fp16
    ln_kernel<<<NTOK, 256, 0, stream>>>(x, ln_g, ln_b, ln16);
    // 2. qkv = ln1 @ w_qkv^T + b_qkv -> fp16   (grid 18x128)
    gemm_f16<0, _Float16, QKVN, DIM><<<dim3(QKVN / 128, NTOK / 128), 256, 0, stream>>>(
        ln16, wq16, b_qkv, nullptr, qkv16);
    // 3. attention (swapped-QK^T MFMA flash) -> fp16
    attn_kernel<<<dim3(SEQ / 64, HEADS, NB), 256, 0, stream>>>(qkv16, attn16);
    // 4. x1 = x + attn @ w_out^T + b_out -> d_out (fp32)   (grid 6x128)
    gemm_f16<1, float, DIM, DIM><<<dim3(DIM / 128, NTOK / 128), 256, 0, stream>>>(
        attn16, wo16, b_out, x, out);
    // 5. ln2 = layernorm(x1) -> fp16
    ln_kernel<<<NTOK, 256, 0, stream>>>(out, ln_g, ln_b, ln16);
    // 6. h = gelu(ln2 @ w_fc1^T + b_fc1) -> fp16   (grid 24x128)
    gemm_f16<2, _Float16, HMLP, DIM><<<dim3(HMLP / 128, NTOK / 128), 256, 0, stream>>>(
        ln16, wf1_16, b_fc1, nullptr, h16);
    // 7. out = x1 + h @ w_fc2^T + b_fc2 -> d_out (fp32)   (grid 6x128)
    gemm_f16<1, float, DIM, HMLP><<<dim3(DIM / 128, NTOK / 128), 256, 0, stream>>>(
        h16, wf2_16, b_fc2, out, out);
}

// Round 13
// 613.994 us; speedup vs baseline: 6.6928x; 1.0700x over previous
//
#include <hip/hip_runtime.h>
#include <math.h>

// Problem dims (fixed by reference)
#define DIM    768
#define NB     16
#define SEQ    1024
#define NTOK   (NB*SEQ)        // 16384
#define HEADS  12
#define HD     64
#define HMLP   3072
#define QKVN   2304

typedef _Float16 f16x8 __attribute__((ext_vector_type(8)));
typedef _Float16 f16x4 __attribute__((ext_vector_type(4)));
typedef float    f32x4 __attribute__((ext_vector_type(4)));

typedef __attribute__((address_space(3))) unsigned int       lds_u32;
typedef __attribute__((address_space(1))) const unsigned int glb_u32;

// async global->LDS, 16 bytes per lane. LDS dest must be linear in lane order.
__device__ __forceinline__ void gload16(const _Float16* g, _Float16* l) {
    __builtin_amdgcn_global_load_lds((glb_u32*)g, (lds_u32*)l, 16, 0, 0);
}

// Exact-GELU via A&S 7.1.26 erf (|err|<1.5e-7): ~12 VALU ops vs ~25-30 for
// libm erff. gelu(x) = 0.5 x (1 + erf(x/sqrt(2))).
__device__ __forceinline__ float gelu_f(float x) {
    const float az = fabsf(x) * 0.70710678118f;
    const float t  = __builtin_amdgcn_rcpf(fmaf(0.3275911f, az, 1.0f));
    float p = fmaf(1.061405429f, t, -1.453152027f);
    p = fmaf(p, t, 1.421413741f);
    p = fmaf(p, t, -0.284496736f);
    p = fmaf(p, t, 0.254829592f);
    p = p * t;
    const float ex  = exp2f(-az * az * 1.44269504f);
    const float erfv = copysignf(fmaf(-p, ex, 1.0f), x);
    return 0.5f * x * (1.0f + erfv);
}

// ---------------------------------------------------------------------------
// LayerNorm: one block per token, 256 threads, 3 elems/thread. fp32 in, fp16 out.
// ---------------------------------------------------------------------------
__global__ __launch_bounds__(256) void ln_kernel(const float* __restrict__ x,
                                                 const float* __restrict__ g,
                                                 const float* __restrict__ b,
                                                 _Float16* __restrict__ out) {
    const int t = blockIdx.x;
    const float* xp = x + (size_t)t * DIM;
    float v[3];
    float s = 0.f, ss = 0.f;
#pragma unroll
    for (int u = 0; u < 3; ++u) {
        v[u] = xp[threadIdx.x + 256 * u];
        s += v[u];
        ss += v[u] * v[u];
    }
#pragma unroll
    for (int m = 1; m < 64; m <<= 1) {
        s  += __shfl_xor(s, m);
        ss += __shfl_xor(ss, m);
    }
    __shared__ float rs[4], rss[4];
    const int wave = threadIdx.x >> 6;
    if ((threadIdx.x & 63) == 0) { rs[wave] = s; rss[wave] = ss; }
    __syncthreads();
    s  = rs[0] + rs[1] + rs[2] + rs[3];
    ss = rss[0] + rss[1] + rss[2] + rss[3];
    const float mu  = s * (1.0f / DIM);
    const float var = ss * (1.0f / DIM) - mu * mu;
    const float rst = 1.0f / sqrtf(var + 1e-5f);
    _Float16* op = out + (size_t)t * DIM;
#pragma unroll
    for (int u = 0; u < 3; ++u) {
        const int c = threadIdx.x + 256 * u;
        op[c] = (_Float16)((v[u] - mu) * rst * g[c] + b[c]);
    }
}

// ---------------------------------------------------------------------------
// Fused fp32 -> fp16 cast of all four weight matrices (dests contiguous in ws).
// Boundaries (elems): wq 1,769,472 | wo +589,824 | wf1 +2,359,296 | wf2 +2,359,296
// ---------------------------------------------------------------------------
__global__ __launch_bounds__(256) void cast4_kernel(const float* __restrict__ s_qkv,
                                                    const float* __restrict__ s_out,
                                                    const float* __restrict__ s_f1,
                                                    const float* __restrict__ s_f2,
                                                    _Float16* __restrict__ dst) {
    const int i = (blockIdx.x * 256 + threadIdx.x) * 4;   // < 7,077,888
    const float* src;
    int off;
    if (i < 1769472)      { src = s_qkv; off = i; }
    else if (i < 2359296) { src = s_out; off = i - 1769472; }
    else if (i < 4718592) { src = s_f1;  off = i - 2359296; }
    else                  { src = s_f2;  off = i - 4718592; }
    const float4 v = *(const float4*)(src + off);
    f16x4 o;
    o[0] = (_Float16)v.x; o[1] = (_Float16)v.y;
    o[2] = (_Float16)v.z; o[3] = (_Float16)v.w;
    *(f16x4*)(dst + i) = o;
}

// ---------------------------------------------------------------------------
// MFMA fp16 GEMM: C[M,N_] = A[M,K_] @ B[N_,K_]^T (+bias, +epilogue), fp32 accum.
// BM=BN=128, BK=32, 256 threads = 4 waves (2x2), 64x64 per wave. Triple-buffered
// static-addressed pipeline (R12-measured structure, kept as-is this round).
// XCD-aware bijective block swizzle. K-slot swizzle on the GLOBAL source.
// EPI: 0 = +bias ; 1 = +bias +residual(fp32) ; 2 = gelu(+bias) poly-exact
// ---------------------------------------------------------------------------
template <int EPI, typename OUT_T, int N_, int K_>
__global__ __launch_bounds__(256) void gemm_f16(const _Float16* __restrict__ A,
                                                const _Float16* __restrict__ Bw,
                                                const float* __restrict__ bias,
                                                const float* __restrict__ res,
                                                OUT_T* __restrict__ C) {
    __shared__ _Float16 As0[128 * 32], As1[128 * 32], As2[128 * 32];
    __shared__ _Float16 Bs0[128 * 32], Bs1[128 * 32], Bs2[128 * 32];

    const int tid  = threadIdx.x;
    const int lane = tid & 63;
    const int wave = tid >> 6;
    const int wr = wave >> 1;
    const int wc = wave & 1;

    const int nwg  = gridDim.x * gridDim.y;
    const int orig = blockIdx.y * gridDim.x + blockIdx.x;
    const int wgid = (orig & 7) * (nwg >> 3) + (orig >> 3);
    const int n0 = (wgid % gridDim.x) * 128;
    const int m0 = (wgid / gridDim.x) * 128;

    const int sr = tid >> 2;           // staging row 0..63
    const int sp = tid & 3;            // staging 16B slot 0..3

    f32x4 acc[4][4] = {};

    const int NT = K_ / 32;            // 24 or 96 — divisible by 3

#define STAGE(SA, SB, k0)                                                     \
    do {                                                                      \
        _Pragma("unroll")                                                     \
        for (int h = 0; h < 2; ++h) {                                         \
            const int r  = sr + h * 64;                                       \
            const int kc = sp ^ ((r >> 1) & 3);                               \
            const size_t goff = (size_t)r * K_ + (k0) + kc * 8;               \
            gload16(A  + (size_t)m0 * K_ + goff, &SA[tid * 8 + h * 2048]);    \
            gload16(Bw + (size_t)n0 * K_ + goff, &SB[tid * 8 + h * 2048]);    \
        }                                                                     \
    } while (0)

#define COMPUTE(CA, CB)                                                       \
    do {                                                                      \
        f16x8 a[4], b[4];                                                     \
        _Pragma("unroll")                                                     \
        for (int m = 0; m < 4; ++m) {                                         \
            const int row = wr * 64 + m * 16 + (lane & 15);                   \
            const int p   = (lane >> 4) ^ ((row >> 1) & 3);                   \
            a[m] = *(const f16x8*)&CA[row * 32 + p * 8];                      \
        }                                                                     \
        _Pragma("unroll")                                                     \
        for (int n = 0; n < 4; ++n) {                                         \
            const int row = wc * 64 + n * 16 + (lane & 15);                   \
            const int p   = (lane >> 4) ^ ((row >> 1) & 3);                   \
            b[n] = *(const f16x8*)&CB[row * 32 + p * 8];                      \
        }                                                                     \
        _Pragma("unroll")                                                     \
        for (int m = 0; m < 4; ++m)                                           \
            _Pragma("unroll")                                                 \
            for (int n = 0; n < 4; ++n)                                       \
                acc[m][n] = __builtin_amdgcn_mfma_f32_16x16x32_f16(           \
                    a[m], b[n], acc[m][n], 0, 0, 0);                          \
    } while (0)

#define STEP(CA, CB, SA, SB)                                                  \
    do {                                                                      \
        if (t + 1 < NT) asm volatile("s_waitcnt vmcnt(4)");                   \
        else            asm volatile("s_waitcnt vmcnt(0)");                   \
        __builtin_amdgcn_sched_barrier(0);                                    \
        __builtin_amdgcn_s_barrier();                                         \
        __builtin_amdgcn_sched_barrier(0);                                    \
        if (t + 2 < NT) STAGE(SA, SB, (t + 2) * 32);                          \
        COMPUTE(CA, CB);                                                      \
        ++t;                                                                  \
    } while (0)

    STAGE(As0, Bs0, 0);
    STAGE(As1, Bs1, 32);
    int t = 0;
    for (int tt = 0; tt < NT / 3; ++tt) {
        STEP(As0, Bs0, As2, Bs2);
        STEP(As1, Bs1, As0, Bs0);
        STEP(As2, Bs2, As1, Bs1);
    }
#undef STEP
#undef COMPUTE
#undef STAGE

    const int col0 = n0 + wc * 64 + (lane & 15);
#pragma unroll
    for (int m = 0; m < 4; ++m) {
#pragma unroll
        for (int j = 0; j < 4; ++j) {
            const size_t row = (size_t)(m0 + wr * 64 + m * 16 + (lane >> 4) * 4 + j);
#pragma unroll
            for (int n = 0; n < 4; ++n) {
                const int col = col0 + n * 16;
                float c = acc[m][n][j] + bias[col];
                if (EPI == 2) c = gelu_f(c);
                if (EPI == 1) c += res[row * N_ + col];
                C[row * N_ + col] = (OUT_T)c;
            }
        }
    }
}

// ---------------------------------------------------------------------------
// MFMA flash attention, SWAPPED QK^T structure (unchanged — validated R6-R12).
// ---------------------------------------------------------------------------
__global__ __launch_bounds__(256) void attn_kernel(const _Float16* __restrict__ qkv,
                                                   _Float16* __restrict__ out) {
    __shared__ _Float16 K_lds[64 * 64];     // [key][64] chunk-XOR swizzled
    __shared__ _Float16 Vt[64 * 72];        // [d][72] transposed, chunk swizzled

    const int q0 = blockIdx.x * 64;
    const int h  = blockIdx.y;
    const int b  = blockIdx.z;
    const float SCALE2 = 0.05205879570f;    // 1/sqrt(768) * log2(e)

    const int tid  = threadIdx.x;
    const int lane = tid & 63;
    const int w    = tid >> 6;
    const int g    = lane >> 4;             // group 0..3
    const int c    = lane & 15;             // col within 16 (q-row for S^T)

    const int skey = tid >> 3;              // V staging key 0..31
    const int sdc  = tid & 7;               // V staging d-chunk 0..7
    const int kkey = tid >> 3;
    const int kchunk = (tid & 7) ^ ((tid >> 3) & 7);   // global chunk for phys slot

    const size_t base = (size_t)b * SEQ * QKVN + (size_t)h * HD;

    f16x8 aq[2];
#pragma unroll
    for (int kk = 0; kk < 2; ++kk)
        aq[kk] = *(const f16x8*)(qkv + base + (size_t)(q0 + w * 16 + c) * QKVN + kk * 32 + g * 8);

    f32x4 o[4] = {};                        // O[q=g*4+j][d=n*16+c]
    float mrow = -1e30f, lrow = 0.f;        // softmax state for q-row c

    for (int kt = 0; kt < 16; ++kt) {
        const int k0 = kt * 64;
        __syncthreads();                    // prev tile LDS reads done
#pragma unroll
        for (int it = 0; it < 2; ++it) {
            const int key = kkey + it * 32;
            gload16(qkv + base + 768 + (size_t)(k0 + key) * QKVN + kchunk * 8,
                    &K_lds[it * 2048 + tid * 8]);
            const int vkey = skey + it * 32;
            const f16x8 vv = *(const f16x8*)(qkv + base + 1536 + (size_t)(k0 + vkey) * QKVN + sdc * 8);
            const int pc = (vkey >> 3) ^ sdc;
#pragma unroll
            for (int e = 0; e < 8; ++e)
                Vt[(sdc * 8 + e) * 72 + pc * 8 + (vkey & 7)] = vv[e];
        }
        __syncthreads();                    // staging complete

        f32x4 s[4] = {};
        __builtin_amdgcn_s_setprio(1);
#pragma unroll
        for (int kb = 0; kb < 4; ++kb) {
#pragma unroll
            for (int kk = 0; kk < 2; ++kk) {
                const f16x8 ak = *(const f16x8*)&K_lds[(kb * 16 + c) * 64 + (((kk * 4 + g) ^ (c & 7)) * 8)];
                s[kb] = __builtin_amdgcn_mfma_f32_16x16x32_f16(ak, aq[kk], s[kb], 0, 0, 0);
            }
        }
        __builtin_amdgcn_s_setprio(0);

        float p[4][4];
        float mx = -1e30f;
#pragma unroll
        for (int kb = 0; kb < 4; ++kb)
#pragma unroll
            for (int j = 0; j < 4; ++j) {
                p[kb][j] = s[kb][j] * SCALE2;
                mx = fmaxf(mx, p[kb][j]);
            }
        mx = fmaxf(mx, __shfl_xor(mx, 16));
        mx = fmaxf(mx, __shfl_xor(mx, 32));
        const float mnew  = fmaxf(mrow, mx);
        const float alpha = exp2f(mrow - mnew);
        float rsum = 0.f;
#pragma unroll
        for (int kb = 0; kb < 4; ++kb)
#pragma unroll
            for (int j = 0; j < 4; ++j) {
                p[kb][j] = exp2f(p[kb][j] - mnew);
                rsum += p[kb][j];
            }
        rsum += __shfl_xor(rsum, 16);
        rsum += __shfl_xor(rsum, 32);
        lrow = lrow * alpha + rsum;
        mrow = mnew;

#pragma unroll
        for (int j = 0; j < 4; ++j) {
            const float aj = __shfl(alpha, g * 4 + j);
#pragma unroll
            for (int n = 0; n < 4; ++n) o[n][j] *= aj;
        }

        f16x8 pa[2];
#pragma unroll
        for (int kk = 0; kk < 2; ++kk)
#pragma unroll
            for (int e = 0; e < 8; ++e)
                pa[kk][e] = (_Float16)p[2 * kk + (e >> 2)][e & 3];

        __builtin_amdgcn_s_setprio(1);
#pragma unroll
        for (int kk = 0; kk < 2; ++kk) {
#pragma unroll
            for (int n = 0; n < 4; ++n) {
                const int d = n * 16 + c;
                const int ch0 = (4 * kk + (g >> 1)) ^ (d >> 3);
                const int ch1 = (4 * kk + 2 + (g >> 1)) ^ (d >> 3);
                union { uint2 r[2]; f16x8 v; } bb;
                bb.r[0] = *(const uint2*)&Vt[d * 72 + ch0 * 8 + (g & 1) * 4];
                bb.r[1] = *(const uint2*)&Vt[d * 72 + ch1 * 8 + (g & 1) * 4];
                o[n] = __builtin_amdgcn_mfma_f32_16x16x32_f16(pa[kk], bb.v, o[n], 0, 0, 0);
            }
        }
        __builtin_amdgcn_s_setprio(0);
    }

#pragma unroll
    for (int j = 0; j < 4; ++j) {
        const float linv = 1.0f / __shfl(lrow, g * 4 + j);
        const size_t row = (size_t)(b * SEQ + q0 + w * 16 + g * 4 + j);
#pragma unroll
        for (int n = 0; n < 4; ++n)
            out[row * DIM + h * HD + n * 16 + c] = (_Float16)(o[n][j] * linv);
    }
}

// ---------------------------------------------------------------------------
// Launch
// ---------------------------------------------------------------------------
extern "C" void kernel_launch(void* const* d_in, const int* in_sizes, int n_in,
                              void* d_out, int out_size, void* d_ws, size_t ws_size,
                              hipStream_t stream) {
    const float* x     = (const float*)d_in[0];
    const float* ln_g  = (const float*)d_in[1];
    const float* ln_b  = (const float*)d_in[2];
    const float* w_qkv = (const float*)d_in[3];
    const float* b_qkv = (const float*)d_in[4];
    const float* w_out = (const float*)d_in[5];
    const float* b_out = (const float*)d_in[6];
    const float* w_fc1 = (const float*)d_in[7];
    const float* b_fc1 = (const float*)d_in[8];
    const float* w_fc2 = (const float*)d_in[9];
    const float* b_fc2 = (const float*)d_in[10];
    float* out = (float*)d_out;

    // Workspace layout (bytes):
    //   wq16   @ 0          : 3,538,944   \
    //   wo16   @ 3,538,944  : 1,179,648    | contiguous — cast4 writes all four
    //   wf1_16 @ 4,718,592  : 4,718,592    |
    //   wf2_16 @ 9,437,184  : 4,718,592   /
    //   ln16   @ 14,155,776 : 25,165,824
    //   qkv16  @ 39,321,600 : 75,497,472
    //   attn16 @114,819,072 : 25,165,824
    //   h16    @ 39,321,600 : 100,663,296 (overlaps qkv16+attn16; both dead by FC1)
    char* ws = (char*)d_ws;
    _Float16* w16    = (_Float16*)(ws);
    _Float16* wq16   = (_Float16*)(ws);
    _Float16* wo16   = (_Float16*)(ws + 3538944);
    _Float16* wf1_16 = (_Float16*)(ws + 4718592);
    _Float16* wf2_16 = (_Float16*)(ws + 9437184);
    _Float16* ln16   = (_Float16*)(ws + 14155776);
    _Float16* qkv16  = (_Float16*)(ws + 39321600);
    _Float16* attn16 = (_Float16*)(ws + 114819072);
    _Float16* h16    = qkv16;

    // fused weight casts (fp32 -> fp16): 7,077,888 elems total, 4/thread
    cast4_kernel<<<6912, 256, 0, stream>>>(w_qkv, w_out, w_fc1, w_fc2, w16);

    // 1. ln1 = layernorm(x) -> fp16
    ln_kernel<<<NTOK, 256, 0, stream>>>(x, ln_g, ln_b, ln16);
    // 2. qkv = ln1 @ w_qkv^T + b_qkv -> fp16   (grid 18x128)
    gemm_f16<0, _Float16, QKVN, DIM><<<dim3(QKVN / 128, NTOK / 128), 256, 0, stream>>>(
        ln16, wq16, b_qkv, nullptr, qkv16);
    // 3. attention (swapped-QK^T MFMA flash) -> fp16
    attn_kernel<<<dim3(SEQ / 64, HEADS, NB), 256, 0, stream>>>(qkv16, attn16);
    // 4. x1 = x + attn @ w_out^T + b_out -> d_out (fp32)   (grid 6x128)
    gemm_f16<1, float, DIM, DIM><<<dim3(DIM / 128, NTOK / 128), 256, 0, stream>>>(
        attn16, wo16, b_out, x, out);
    // 5. ln2 = layernorm(x1) -> fp16
    ln_kernel<<<NTOK, 256, 0, stream>>>(out, ln_g, ln_b, ln16);
    // 6. h = gelu(ln2 @ w_fc1^T + b_fc1) -> fp16   (grid 24x128)
    gemm_f16<2, _Float16, HMLP, DIM><<<dim3(HMLP / 128, NTOK / 128), 256, 0, stream>>>(
        ln16, wf1_16, b_fc1, nullptr, h16);
    // 7. out = x1 + h @ w_fc2^T + b_fc2 -> d_out (fp32)   (grid 6x128)
    gemm_f16<1, float, DIM, HMLP><<<dim3(DIM / 128, NTOK / 128), 256, 0, stream>>>(
        h16, wf2_16, b_fc2, out, out);
}